// Round 1
// baseline (1254.849 us; speedup 1.0000x reference)
//
#include <hip/hip_runtime.h>

#define N_NODES 50000
#define E_EDGES 800000
#define HID 128

// ---------------- LayerNorm 1: one wave per node, lane = 2 channels ----------
__global__ __launch_bounds__(256) void ln_kernel(
    const float* __restrict__ x, const float* __restrict__ g,
    const float* __restrict__ b, float* __restrict__ out, int n)
{
  int node = (blockIdx.x * blockDim.x + threadIdx.x) >> 6;
  if (node >= n) return;
  int lane = threadIdx.x & 63;
  const float* row = x + (size_t)node * HID;
  float2 v = *(const float2*)(row + lane * 2);
  float s = v.x + v.y;
  for (int m = 32; m >= 1; m >>= 1) s += __shfl_xor(s, m);
  float mu = s * (1.0f / 128.0f);
  float dx = v.x - mu, dy = v.y - mu;
  float ss = dx * dx + dy * dy;
  for (int m = 32; m >= 1; m >>= 1) ss += __shfl_xor(ss, m);
  float rs = rsqrtf(ss * (1.0f / 128.0f) + 1e-5f);
  float2 gg = *(const float2*)(g + lane * 2);
  float2 bb = *(const float2*)(b + lane * 2);
  float2 o;
  o.x = dx * rs * gg.x + bb.x;
  o.y = dy * rs * gg.y + bb.y;
  *(float2*)(out + (size_t)node * HID + lane * 2) = o;
}

// ------------- QKVS: 32-node tile in LDS; thread owns (matrix, 2 cols) -------
#define TILE_N 32
__global__ __launch_bounds__(256) void qkvs_kernel(
    const float* __restrict__ ln1,
    const float* __restrict__ Wq, const float* __restrict__ bq,
    const float* __restrict__ Wk, const float* __restrict__ bk,
    const float* __restrict__ Wv, const float* __restrict__ bv,
    const float* __restrict__ Ws, const float* __restrict__ bs,
    float* __restrict__ q, float* __restrict__ k, float* __restrict__ v,
    float* __restrict__ s, int n)
{
  __shared__ float lh[TILE_N][HID];
  int node0 = blockIdx.x * TILE_N;
  int tid = threadIdx.x;
  for (int i = tid; i < TILE_N * HID / 4; i += 256) {
    int nn = i >> 5, c4 = i & 31;
    float4 val = make_float4(0, 0, 0, 0);
    if (node0 + nn < n) val = *(const float4*)(ln1 + (size_t)(node0 + nn) * HID + c4 * 4);
    *(float4*)&lh[nn][c4 * 4] = val;
  }
  __syncthreads();
  int mat = tid >> 6;
  int ca = (tid & 63) * 2, cb = ca + 1;
  const float* W; const float* bias; float* outp;
  switch (mat) {
    case 0: W = Wq; bias = bq; outp = q; break;
    case 1: W = Wk; bias = bk; outp = k; break;
    case 2: W = Wv; bias = bv; outp = v; break;
    default: W = Ws; bias = bs; outp = s; break;
  }
  float acc_a[TILE_N], acc_b[TILE_N];
  float ba = bias[ca], bbv = bias[cb];
  #pragma unroll
  for (int nn = 0; nn < TILE_N; nn++) { acc_a[nn] = ba; acc_b[nn] = bbv; }
  const float* Wa = W + (size_t)ca * HID;
  const float* Wb = W + (size_t)cb * HID;
  for (int k4 = 0; k4 < HID / 4; k4++) {
    float4 wa = *(const float4*)(Wa + k4 * 4);
    float4 wb = *(const float4*)(Wb + k4 * 4);
    #pragma unroll
    for (int nn = 0; nn < TILE_N; nn++) {
      float4 h4 = *(const float4*)&lh[nn][k4 * 4];
      acc_a[nn] += h4.x * wa.x + h4.y * wa.y + h4.z * wa.z + h4.w * wa.w;
      acc_b[nn] += h4.x * wb.x + h4.y * wb.y + h4.z * wb.z + h4.w * wb.w;
    }
  }
  for (int nn = 0; nn < TILE_N; nn++) {
    int node = node0 + nn;
    if (node < n) {
      float2 o = make_float2(acc_a[nn], acc_b[nn]);
      *(float2*)(outp + (size_t)node * HID + ca) = o;
    }
  }
}

// -------- Edge kernel: 1 wave per edge; lane = channels 2l,2l+1; head = l/16 -
__global__ __launch_bounds__(256) void edge_kernel(
    const int* __restrict__ ei, const float* __restrict__ attr,
    const float* __restrict__ We,
    const float* __restrict__ q, const float* __restrict__ k,
    const float* __restrict__ v,
    float* __restrict__ accum, float* __restrict__ denom)
{
  int e = (blockIdx.x << 2) + (threadIdx.x >> 6);
  if (e >= E_EDGES) return;
  int lane = threadIdx.x & 63;
  int src = ei[e];
  int dst = ei[E_EDGES + e];
  float4 a4 = *(const float4*)(attr + (size_t)e * 4);
  int c0 = lane * 2;
  float4 w0 = *(const float4*)(We + c0 * 4);
  float4 w1 = *(const float4*)(We + c0 * 4 + 4);
  float e0 = a4.x * w0.x + a4.y * w0.y + a4.z * w0.z + a4.w * w0.w;
  float e1 = a4.x * w1.x + a4.y * w1.y + a4.z * w1.z + a4.w * w1.w;
  float2 qd = *(const float2*)(q + (size_t)dst * HID + c0);
  float2 ks = *(const float2*)(k + (size_t)src * HID + c0);
  float2 vs = *(const float2*)(v + (size_t)src * HID + c0);
  float kj0 = ks.x + e0, kj1 = ks.y + e1;
  float part = qd.x * kj0 + qd.y * kj1;
  part += __shfl_xor(part, 1);
  part += __shfl_xor(part, 2);
  part += __shfl_xor(part, 4);
  part += __shfl_xor(part, 8);
  float alpha = part * 0.17677669529663687f;  // 1/sqrt(32)
  float a = expf(alpha);                      // max-free softmax (alpha ~ N(0,0.33))
  float vj0 = vs.x + e0, vj1 = vs.y + e1;
  atomicAdd(accum + (size_t)dst * HID + c0, a * vj0);
  atomicAdd(accum + (size_t)dst * HID + c0 + 1, a * vj1);
  if ((lane & 15) == 0) atomicAdd(denom + dst * 4 + (lane >> 4), a);
}

// ------- Combine: normalize, beta gate, first residual. One wave per node ----
__global__ __launch_bounds__(256) void combine_kernel(
    const float* __restrict__ x, const float* __restrict__ accum,
    const float* __restrict__ denom, const float* __restrict__ sk,
    const float* __restrict__ Wb, float* __restrict__ xn, int n)
{
  int node = (blockIdx.x * blockDim.x + threadIdx.x) >> 6;
  if (node >= n) return;
  int lane = threadIdx.x & 63;
  int c0 = lane * 2;
  int h = lane >> 4;
  float inv = 1.0f / (denom[node * 4 + h] + 1e-16f);
  float2 acc2 = *(const float2*)(accum + (size_t)node * HID + c0);
  float o0 = acc2.x * inv, o1 = acc2.y * inv;
  float2 skp = *(const float2*)(sk + (size_t)node * HID + c0);
  float wb_o0 = Wb[c0] + Wb[256 + c0];
  float wb_o1 = Wb[c0 + 1] + Wb[256 + c0 + 1];
  float wb_s0 = Wb[128 + c0] - Wb[256 + c0];
  float wb_s1 = Wb[128 + c0 + 1] - Wb[256 + c0 + 1];
  float part = o0 * wb_o0 + o1 * wb_o1 + skp.x * wb_s0 + skp.y * wb_s1;
  for (int m = 32; m >= 1; m >>= 1) part += __shfl_xor(part, m);
  float beta = 1.0f / (1.0f + expf(-part));
  float h0 = beta * skp.x + (1.0f - beta) * o0;
  float h1 = beta * skp.y + (1.0f - beta) * o1;
  float2 xv = *(const float2*)(x + (size_t)node * HID + c0);
  *(float2*)(xn + (size_t)node * HID + c0) = make_float2(xv.x + h0, xv.y + h1);
}

// ------- LN2 + MLP fused: 16 nodes per block, t[16][512] in LDS --------------
#define MT 16
__global__ __launch_bounds__(256) void mlp_kernel(
    const float* __restrict__ xn,
    const float* __restrict__ g2, const float* __restrict__ b2ln,
    const float* __restrict__ W1, const float* __restrict__ b1,
    const float* __restrict__ W2, const float* __restrict__ b2,
    float* __restrict__ out, int n)
{
  __shared__ float sxn[MT][HID];
  __shared__ float sln[MT][HID];
  __shared__ float st[MT][512];
  int node0 = blockIdx.x * MT;
  int tid = threadIdx.x;
  for (int i = tid; i < MT * HID / 4; i += 256) {
    int nn = i >> 5, c4 = i & 31;
    float4 val = make_float4(0, 0, 0, 0);
    if (node0 + nn < n) val = *(const float4*)(xn + (size_t)(node0 + nn) * HID + c4 * 4);
    *(float4*)&sxn[nn][c4 * 4] = val;
  }
  __syncthreads();
  {
    int grp = tid >> 4;  // node within tile
    int gl = tid & 15;
    float vals[8];
    float sum = 0.f, sq = 0.f;
    #pragma unroll
    for (int j = 0; j < 8; j++) { vals[j] = sxn[grp][gl * 8 + j]; sum += vals[j]; }
    for (int m = 8; m >= 1; m >>= 1) sum += __shfl_xor(sum, m);
    float mu = sum * (1.0f / 128.0f);
    #pragma unroll
    for (int j = 0; j < 8; j++) { float d = vals[j] - mu; sq += d * d; }
    for (int m = 8; m >= 1; m >>= 1) sq += __shfl_xor(sq, m);
    float rs = rsqrtf(sq * (1.0f / 128.0f) + 1e-5f);
    #pragma unroll
    for (int j = 0; j < 8; j++) {
      int c = gl * 8 + j;
      sln[grp][c] = (vals[j] - mu) * rs * g2[c] + b2ln[c];
    }
  }
  __syncthreads();
  {
    int ja = tid * 2, jb = ja + 1;
    float acc_a[MT], acc_b[MT];
    float ba = b1[ja], bb = b1[jb];
    #pragma unroll
    for (int nn = 0; nn < MT; nn++) { acc_a[nn] = ba; acc_b[nn] = bb; }
    const float* Wa = W1 + (size_t)ja * HID;
    const float* Wb = W1 + (size_t)jb * HID;
    for (int k4 = 0; k4 < 32; k4++) {
      float4 wa = *(const float4*)(Wa + k4 * 4);
      float4 wb = *(const float4*)(Wb + k4 * 4);
      #pragma unroll
      for (int nn = 0; nn < MT; nn++) {
        float4 h4 = *(const float4*)&sln[nn][k4 * 4];
        acc_a[nn] += h4.x * wa.x + h4.y * wa.y + h4.z * wa.z + h4.w * wa.w;
        acc_b[nn] += h4.x * wb.x + h4.y * wb.y + h4.z * wb.z + h4.w * wb.w;
      }
    }
    #pragma unroll
    for (int nn = 0; nn < MT; nn++) {
      st[nn][ja] = fmaxf(acc_a[nn], 0.0f);
      st[nn][jb] = fmaxf(acc_b[nn], 0.0f);
    }
  }
  __syncthreads();
  {
    int c = tid & 127;
    int nh = tid >> 7;
    const float* Wr = W2 + (size_t)c * 512;
    float accs[8];
    float bc = b2[c];
    #pragma unroll
    for (int i = 0; i < 8; i++) accs[i] = bc;
    for (int j4 = 0; j4 < 128; j4++) {
      float4 w4 = *(const float4*)(Wr + j4 * 4);
      #pragma unroll
      for (int i = 0; i < 8; i++) {
        float4 t4 = *(const float4*)&st[nh * 8 + i][j4 * 4];
        accs[i] += t4.x * w4.x + t4.y * w4.y + t4.z * w4.z + t4.w * w4.w;
      }
    }
    #pragma unroll
    for (int i = 0; i < 8; i++) {
      int nn = nh * 8 + i;
      int node = node0 + nn;
      if (node < n) out[(size_t)node * HID + c] = sxn[nn][c] + accs[i];
    }
  }
}

extern "C" void kernel_launch(void* const* d_in, const int* in_sizes, int n_in,
                              void* d_out, int out_size, void* d_ws, size_t ws_size,
                              hipStream_t stream) {
  const float* x     = (const float*)d_in[0];
  const int*   ei    = (const int*)d_in[1];
  const float* attr  = (const float*)d_in[2];
  const float* ln1_g = (const float*)d_in[3];
  const float* ln1_b = (const float*)d_in[4];
  const float* Wq    = (const float*)d_in[5];
  const float* bq    = (const float*)d_in[6];
  const float* Wk    = (const float*)d_in[7];
  const float* bk    = (const float*)d_in[8];
  const float* Wv    = (const float*)d_in[9];
  const float* bv    = (const float*)d_in[10];
  const float* We    = (const float*)d_in[11];
  const float* Wskip = (const float*)d_in[12];
  const float* bskip = (const float*)d_in[13];
  const float* Wbeta = (const float*)d_in[14];
  const float* ln2_g = (const float*)d_in[15];
  const float* ln2_b = (const float*)d_in[16];
  const float* W1    = (const float*)d_in[17];
  const float* b1    = (const float*)d_in[18];
  const float* W2    = (const float*)d_in[19];
  const float* b2    = (const float*)d_in[20];
  float* out = (float*)d_out;
  float* ws  = (float*)d_ws;

  size_t NH = (size_t)N_NODES * HID;
  float* ln1   = ws;            // reused as xn after combine
  float* q     = ws + NH;
  float* k     = ws + 2 * NH;
  float* v     = ws + 3 * NH;
  float* s     = ws + 4 * NH;
  float* accum = ws + 5 * NH;
  float* denom = ws + 6 * NH;   // N*4 floats

  hipMemsetAsync(accum, 0, NH * sizeof(float), stream);
  hipMemsetAsync(denom, 0, (size_t)N_NODES * 4 * sizeof(float), stream);

  ln_kernel<<<(N_NODES + 3) / 4, 256, 0, stream>>>(x, ln1_g, ln1_b, ln1, N_NODES);
  qkvs_kernel<<<(N_NODES + TILE_N - 1) / TILE_N, 256, 0, stream>>>(
      ln1, Wq, bq, Wk, bk, Wv, bv, Wskip, bskip, q, k, v, s, N_NODES);
  edge_kernel<<<E_EDGES / 4, 256, 0, stream>>>(ei, attr, We, q, k, v, accum, denom);
  combine_kernel<<<(N_NODES + 3) / 4, 256, 0, stream>>>(
      x, accum, denom, s, Wbeta, ln1 /*xn*/, N_NODES);
  mlp_kernel<<<(N_NODES + MT - 1) / MT, 256, 0, stream>>>(
      ln1, ln2_g, ln2_b, W1, b1, W2, b2, out, N_NODES);
}

// Round 2
// 855.747 us; speedup vs baseline: 1.4664x; 1.4664x over previous
//
#include <hip/hip_runtime.h>

#define N_NODES 50000
#define E_EDGES 800000
#define HID 128

// ---------------- LayerNorm 1: one wave per node, lane = 2 channels ----------
__global__ __launch_bounds__(256) void ln_kernel(
    const float* __restrict__ x, const float* __restrict__ g,
    const float* __restrict__ b, float* __restrict__ out, int n)
{
  int node = (blockIdx.x * blockDim.x + threadIdx.x) >> 6;
  if (node >= n) return;
  int lane = threadIdx.x & 63;
  const float* row = x + (size_t)node * HID;
  float2 v = *(const float2*)(row + lane * 2);
  float s = v.x + v.y;
  for (int m = 32; m >= 1; m >>= 1) s += __shfl_xor(s, m);
  float mu = s * (1.0f / 128.0f);
  float dx = v.x - mu, dy = v.y - mu;
  float ss = dx * dx + dy * dy;
  for (int m = 32; m >= 1; m >>= 1) ss += __shfl_xor(ss, m);
  float rs = rsqrtf(ss * (1.0f / 128.0f) + 1e-5f);
  float2 gg = *(const float2*)(g + lane * 2);
  float2 bb = *(const float2*)(b + lane * 2);
  float2 o;
  o.x = dx * rs * gg.x + bb.x;
  o.y = dy * rs * gg.y + bb.y;
  *(float2*)(out + (size_t)node * HID + lane * 2) = o;
}

// ------------- QKVS: 32-node tile in LDS; thread owns (matrix, 2 cols) -------
#define TILE_N 32
__global__ __launch_bounds__(256) void qkvs_kernel(
    const float* __restrict__ ln1,
    const float* __restrict__ Wq, const float* __restrict__ bq,
    const float* __restrict__ Wk, const float* __restrict__ bk,
    const float* __restrict__ Wv, const float* __restrict__ bv,
    const float* __restrict__ Ws, const float* __restrict__ bs,
    float* __restrict__ q, float* __restrict__ k, float* __restrict__ v,
    float* __restrict__ s, int n)
{
  __shared__ float lh[TILE_N][HID];
  int node0 = blockIdx.x * TILE_N;
  int tid = threadIdx.x;
  for (int i = tid; i < TILE_N * HID / 4; i += 256) {
    int nn = i >> 5, c4 = i & 31;
    float4 val = make_float4(0, 0, 0, 0);
    if (node0 + nn < n) val = *(const float4*)(ln1 + (size_t)(node0 + nn) * HID + c4 * 4);
    *(float4*)&lh[nn][c4 * 4] = val;
  }
  __syncthreads();
  int mat = tid >> 6;
  int ca = (tid & 63) * 2, cb = ca + 1;
  const float* W; const float* bias; float* outp;
  switch (mat) {
    case 0: W = Wq; bias = bq; outp = q; break;
    case 1: W = Wk; bias = bk; outp = k; break;
    case 2: W = Wv; bias = bv; outp = v; break;
    default: W = Ws; bias = bs; outp = s; break;
  }
  float acc_a[TILE_N], acc_b[TILE_N];
  float ba = bias[ca], bbv = bias[cb];
  #pragma unroll
  for (int nn = 0; nn < TILE_N; nn++) { acc_a[nn] = ba; acc_b[nn] = bbv; }
  const float* Wa = W + (size_t)ca * HID;
  const float* Wb = W + (size_t)cb * HID;
  for (int k4 = 0; k4 < HID / 4; k4++) {
    float4 wa = *(const float4*)(Wa + k4 * 4);
    float4 wb = *(const float4*)(Wb + k4 * 4);
    #pragma unroll
    for (int nn = 0; nn < TILE_N; nn++) {
      float4 h4 = *(const float4*)&lh[nn][k4 * 4];
      acc_a[nn] += h4.x * wa.x + h4.y * wa.y + h4.z * wa.z + h4.w * wa.w;
      acc_b[nn] += h4.x * wb.x + h4.y * wb.y + h4.z * wb.z + h4.w * wb.w;
    }
  }
  for (int nn = 0; nn < TILE_N; nn++) {
    int node = node0 + nn;
    if (node < n) {
      float2 o = make_float2(acc_a[nn], acc_b[nn]);
      *(float2*)(outp + (size_t)node * HID + ca) = o;
    }
  }
}

// -------- CSR build: count degrees ------------------------------------------
__global__ __launch_bounds__(256) void count_kernel(
    const int* __restrict__ ei, int* __restrict__ deg)
{
  int e = blockIdx.x * 256 + threadIdx.x;
  if (e < E_EDGES) atomicAdd(deg + ei[E_EDGES + e], 1);
}

// -------- CSR build: exclusive scan (single block, 1024 threads) -------------
__global__ __launch_bounds__(1024) void scan_kernel(
    const int* __restrict__ deg, int* __restrict__ row_start,
    int* __restrict__ cursor, int n)
{
  __shared__ int sums[1024];
  int tid = threadIdx.x;
  int chunk = (n + 1023) / 1024;
  int start = tid * chunk;
  int end = min(start + chunk, n);
  int s = 0;
  for (int i = start; i < end; i++) s += deg[i];
  sums[tid] = s;
  __syncthreads();
  for (int off = 1; off < 1024; off <<= 1) {
    int t = (tid >= off) ? sums[tid - off] : 0;
    __syncthreads();
    sums[tid] += t;
    __syncthreads();
  }
  int run = sums[tid] - s;  // exclusive base for this thread's chunk
  for (int i = start; i < end; i++) {
    row_start[i] = run;
    cursor[i] = run;
    run += deg[i];
  }
}

// -------- CSR build: scatter packed (src, attr) records ----------------------
__global__ __launch_bounds__(256) void scatter_kernel(
    const int* __restrict__ ei, const float4* __restrict__ attr,
    int* __restrict__ cursor,
    int* __restrict__ csr_src, float4* __restrict__ csr_attr)
{
  int e = blockIdx.x * 256 + threadIdx.x;
  if (e >= E_EDGES) return;
  int dst = ei[E_EDGES + e];
  int pos = atomicAdd(cursor + dst, 1);
  csr_src[pos] = ei[e];
  csr_attr[pos] = attr[e];
}

// -------- Gather + combine: 1 wave per dst node, lane = 2 channels -----------
__global__ __launch_bounds__(256) void gather_kernel(
    const int* __restrict__ row_start, const int* __restrict__ deg,
    const int* __restrict__ csr_src, const float4* __restrict__ csr_attr,
    const float* __restrict__ We,
    const float* __restrict__ q, const float* __restrict__ k,
    const float* __restrict__ v,
    const float* __restrict__ x, const float* __restrict__ sk,
    const float* __restrict__ Wb, float* __restrict__ xn, int n)
{
  int node = (blockIdx.x * blockDim.x + threadIdx.x) >> 6;
  if (node >= n) return;
  int lane = threadIdx.x & 63;
  int c0 = lane * 2;
  float4 w0 = *(const float4*)(We + c0 * 4);
  float4 w1 = *(const float4*)(We + c0 * 4 + 4);
  float2 qd = *(const float2*)(q + (size_t)node * HID + c0);
  float acc0 = 0.f, acc1 = 0.f, den = 0.f;
  int rs = row_start[node];
  int re = rs + deg[node];
  for (int j = rs; j < re; j++) {
    int src = csr_src[j];
    float4 a4 = csr_attr[j];
    float e0 = a4.x * w0.x + a4.y * w0.y + a4.z * w0.z + a4.w * w0.w;
    float e1 = a4.x * w1.x + a4.y * w1.y + a4.z * w1.z + a4.w * w1.w;
    float2 ks = *(const float2*)(k + (size_t)src * HID + c0);
    float2 vs = *(const float2*)(v + (size_t)src * HID + c0);
    float kj0 = ks.x + e0, kj1 = ks.y + e1;
    float part = qd.x * kj0 + qd.y * kj1;
    part += __shfl_xor(part, 1);
    part += __shfl_xor(part, 2);
    part += __shfl_xor(part, 4);
    part += __shfl_xor(part, 8);
    float a = expf(part * 0.17677669529663687f);  // 1/sqrt(32); max-free softmax
    acc0 += a * (vs.x + e0);
    acc1 += a * (vs.y + e1);
    den += a;  // identical across the 16-lane head group
  }
  float inv = 1.0f / (den + 1e-16f);
  float o0 = acc0 * inv, o1 = acc1 * inv;
  // ---- fused combine: beta gate + first residual ----
  float2 skp = *(const float2*)(sk + (size_t)node * HID + c0);
  float wb_o0 = Wb[c0] + Wb[256 + c0];
  float wb_o1 = Wb[c0 + 1] + Wb[256 + c0 + 1];
  float wb_s0 = Wb[128 + c0] - Wb[256 + c0];
  float wb_s1 = Wb[128 + c0 + 1] - Wb[256 + c0 + 1];
  float bpart = o0 * wb_o0 + o1 * wb_o1 + skp.x * wb_s0 + skp.y * wb_s1;
  for (int m = 32; m >= 1; m >>= 1) bpart += __shfl_xor(bpart, m);
  float beta = 1.0f / (1.0f + expf(-bpart));
  float h0 = beta * skp.x + (1.0f - beta) * o0;
  float h1 = beta * skp.y + (1.0f - beta) * o1;
  float2 xv = *(const float2*)(x + (size_t)node * HID + c0);
  *(float2*)(xn + (size_t)node * HID + c0) = make_float2(xv.x + h0, xv.y + h1);
}

// ------- LN2 + MLP fused: 16 nodes per block, t[16][512] in LDS --------------
#define MT 16
__global__ __launch_bounds__(256) void mlp_kernel(
    const float* __restrict__ xn,
    const float* __restrict__ g2, const float* __restrict__ b2ln,
    const float* __restrict__ W1, const float* __restrict__ b1,
    const float* __restrict__ W2, const float* __restrict__ b2,
    float* __restrict__ out, int n)
{
  __shared__ float sxn[MT][HID];
  __shared__ float sln[MT][HID];
  __shared__ float st[MT][512];
  int node0 = blockIdx.x * MT;
  int tid = threadIdx.x;
  for (int i = tid; i < MT * HID / 4; i += 256) {
    int nn = i >> 5, c4 = i & 31;
    float4 val = make_float4(0, 0, 0, 0);
    if (node0 + nn < n) val = *(const float4*)(xn + (size_t)(node0 + nn) * HID + c4 * 4);
    *(float4*)&sxn[nn][c4 * 4] = val;
  }
  __syncthreads();
  {
    int grp = tid >> 4;  // node within tile
    int gl = tid & 15;
    float vals[8];
    float sum = 0.f, sq = 0.f;
    #pragma unroll
    for (int j = 0; j < 8; j++) { vals[j] = sxn[grp][gl * 8 + j]; sum += vals[j]; }
    for (int m = 8; m >= 1; m >>= 1) sum += __shfl_xor(sum, m);
    float mu = sum * (1.0f / 128.0f);
    #pragma unroll
    for (int j = 0; j < 8; j++) { float d = vals[j] - mu; sq += d * d; }
    for (int m = 8; m >= 1; m >>= 1) sq += __shfl_xor(sq, m);
    float rs = rsqrtf(sq * (1.0f / 128.0f) + 1e-5f);
    #pragma unroll
    for (int j = 0; j < 8; j++) {
      int c = gl * 8 + j;
      sln[grp][c] = (vals[j] - mu) * rs * g2[c] + b2ln[c];
    }
  }
  __syncthreads();
  {
    int ja = tid * 2, jb = ja + 1;
    float acc_a[MT], acc_b[MT];
    float ba = b1[ja], bb = b1[jb];
    #pragma unroll
    for (int nn = 0; nn < MT; nn++) { acc_a[nn] = ba; acc_b[nn] = bb; }
    const float* Wa = W1 + (size_t)ja * HID;
    const float* Wb = W1 + (size_t)jb * HID;
    for (int k4 = 0; k4 < 32; k4++) {
      float4 wa = *(const float4*)(Wa + k4 * 4);
      float4 wb = *(const float4*)(Wb + k4 * 4);
      #pragma unroll
      for (int nn = 0; nn < MT; nn++) {
        float4 h4 = *(const float4*)&sln[nn][k4 * 4];
        acc_a[nn] += h4.x * wa.x + h4.y * wa.y + h4.z * wa.z + h4.w * wa.w;
        acc_b[nn] += h4.x * wb.x + h4.y * wb.y + h4.z * wb.z + h4.w * wb.w;
      }
    }
    #pragma unroll
    for (int nn = 0; nn < MT; nn++) {
      st[nn][ja] = fmaxf(acc_a[nn], 0.0f);
      st[nn][jb] = fmaxf(acc_b[nn], 0.0f);
    }
  }
  __syncthreads();
  {
    int c = tid & 127;
    int nh = tid >> 7;
    const float* Wr = W2 + (size_t)c * 512;
    float accs[8];
    float bc = b2[c];
    #pragma unroll
    for (int i = 0; i < 8; i++) accs[i] = bc;
    for (int j4 = 0; j4 < 128; j4++) {
      float4 w4 = *(const float4*)(Wr + j4 * 4);
      #pragma unroll
      for (int i = 0; i < 8; i++) {
        float4 t4 = *(const float4*)&st[nh * 8 + i][j4 * 4];
        accs[i] += t4.x * w4.x + t4.y * w4.y + t4.z * w4.z + t4.w * w4.w;
      }
    }
    #pragma unroll
    for (int i = 0; i < 8; i++) {
      int nn = nh * 8 + i;
      int node = node0 + nn;
      if (node < n) out[(size_t)node * HID + c] = sxn[nn][c] + accs[i];
    }
  }
}

extern "C" void kernel_launch(void* const* d_in, const int* in_sizes, int n_in,
                              void* d_out, int out_size, void* d_ws, size_t ws_size,
                              hipStream_t stream) {
  const float* x     = (const float*)d_in[0];
  const int*   ei    = (const int*)d_in[1];
  const float* attr  = (const float*)d_in[2];
  const float* ln1_g = (const float*)d_in[3];
  const float* ln1_b = (const float*)d_in[4];
  const float* Wq    = (const float*)d_in[5];
  const float* bq    = (const float*)d_in[6];
  const float* Wk    = (const float*)d_in[7];
  const float* bk    = (const float*)d_in[8];
  const float* Wv    = (const float*)d_in[9];
  const float* bv    = (const float*)d_in[10];
  const float* We    = (const float*)d_in[11];
  const float* Wskip = (const float*)d_in[12];
  const float* bskip = (const float*)d_in[13];
  const float* Wbeta = (const float*)d_in[14];
  const float* ln2_g = (const float*)d_in[15];
  const float* ln2_b = (const float*)d_in[16];
  const float* W1    = (const float*)d_in[17];
  const float* b1    = (const float*)d_in[18];
  const float* W2    = (const float*)d_in[19];
  const float* b2    = (const float*)d_in[20];
  float* out = (float*)d_out;
  float* ws  = (float*)d_ws;

  size_t NH = (size_t)N_NODES * HID;
  float* ln1 = ws;              // reused as xn after gather/combine
  float* q   = ws + NH;
  float* k   = ws + 2 * NH;
  float* v   = ws + 3 * NH;
  float* s   = ws + 4 * NH;
  int* deg       = (int*)(ws + 5 * NH);
  int* row_start = deg + N_NODES;
  int* cursor    = row_start + N_NODES;
  int* csr_src   = cursor + N_NODES;
  // 3*N + E ints = 950000 (multiple of 4) -> csr_attr stays 16B-aligned
  float4* csr_attr = (float4*)(ws + 5 * NH + 950000);

  hipMemsetAsync(deg, 0, N_NODES * sizeof(int), stream);

  ln_kernel<<<(N_NODES + 3) / 4, 256, 0, stream>>>(x, ln1_g, ln1_b, ln1, N_NODES);
  qkvs_kernel<<<(N_NODES + TILE_N - 1) / TILE_N, 256, 0, stream>>>(
      ln1, Wq, bq, Wk, bk, Wv, bv, Wskip, bskip, q, k, v, s, N_NODES);
  count_kernel<<<(E_EDGES + 255) / 256, 256, 0, stream>>>(ei, deg);
  scan_kernel<<<1, 1024, 0, stream>>>(deg, row_start, cursor, N_NODES);
  scatter_kernel<<<(E_EDGES + 255) / 256, 256, 0, stream>>>(
      ei, (const float4*)attr, cursor, csr_src, csr_attr);
  gather_kernel<<<(N_NODES * 64 + 255) / 256, 256, 0, stream>>>(
      row_start, deg, csr_src, csr_attr, We, q, k, v, x, s, Wbeta,
      ln1 /*xn*/, N_NODES);
  mlp_kernel<<<(N_NODES + MT - 1) / MT, 256, 0, stream>>>(
      ln1, ln2_g, ln2_b, W1, b1, W2, b2, out, N_NODES);
}

// Round 3
// 514.966 us; speedup vs baseline: 2.4368x; 1.6618x over previous
//
#include <hip/hip_runtime.h>

#define N_NODES 50000
#define E_EDGES 800000
#define HID 128

typedef __attribute__((ext_vector_type(8))) short short8;
typedef __attribute__((ext_vector_type(4))) float f32x4;

static __device__ __forceinline__ unsigned short f2bf(float f) {
  unsigned int u = __builtin_bit_cast(unsigned int, f);
  u += 0x7fff + ((u >> 16) & 1);  // round-to-nearest-even
  return (unsigned short)(u >> 16);
}

// ---- weight conversion fp32 -> bf16 (Wq|Wk|Wv|Wskip stacked, W1, W2) --------
__global__ __launch_bounds__(256) void wcvt_kernel(
    const float4* __restrict__ Wq, const float4* __restrict__ Wk,
    const float4* __restrict__ Wv, const float4* __restrict__ Ws,
    const float4* __restrict__ W1, const float4* __restrict__ W2,
    unsigned short* __restrict__ wqkvs, unsigned short* __restrict__ w1b,
    unsigned short* __restrict__ w2b)
{
  int i = blockIdx.x * 256 + threadIdx.x;  // [0, 49152) float4 groups
  const float4* src;
  unsigned short* dst;
  if (i < 16384) {
    int part = i >> 12;
    src = ((part == 0) ? Wq : (part == 1) ? Wk : (part == 2) ? Wv : Ws) + (i & 4095);
    dst = wqkvs + i * 4;
  } else if (i < 32768) {
    src = W1 + (i - 16384); dst = w1b + (size_t)(i - 16384) * 4;
  } else {
    src = W2 + (i - 32768); dst = w2b + (size_t)(i - 32768) * 4;
  }
  float4 v = *src;
  ushort4 o;
  o.x = f2bf(v.x); o.y = f2bf(v.y); o.z = f2bf(v.z); o.w = f2bf(v.w);
  *(ushort4*)dst = o;
}

// ---- fused LN1 + QKVS projection via bf16 MFMA ------------------------------
// block: 256 thr, 64 nodes. A-tile (LN output) bf16 in LDS, XOR-swizzled.
__global__ __launch_bounds__(256) void qkvs_kernel(
    const float* __restrict__ x,
    const float* __restrict__ g1, const float* __restrict__ bln,
    const unsigned short* __restrict__ wqkvs,
    const float* __restrict__ bq, const float* __restrict__ bk,
    const float* __restrict__ bv, const float* __restrict__ bs,
    float* __restrict__ q, float* __restrict__ k, float* __restrict__ v,
    float* __restrict__ s, int n)
{
  __shared__ short lnA[64][128];
  int node0 = blockIdx.x * 64;
  int tid = threadIdx.x;
  int g = tid >> 4, gl = tid & 15, c0 = gl * 8;
  float gv[8], bv2[8];
  *(float4*)&gv[0] = *(const float4*)(g1 + c0);
  *(float4*)&gv[4] = *(const float4*)(g1 + c0 + 4);
  *(float4*)&bv2[0] = *(const float4*)(bln + c0);
  *(float4*)&bv2[4] = *(const float4*)(bln + c0 + 4);
  for (int ni = 0; ni < 4; ni++) {
    int nl = ni * 16 + g;
    int node = node0 + nl;
    short8 h8 = {0, 0, 0, 0, 0, 0, 0, 0};
    if (node < n) {
      float vals[8];
      const float* row = x + (size_t)node * HID + c0;
      *(float4*)&vals[0] = *(const float4*)row;
      *(float4*)&vals[4] = *(const float4*)(row + 4);
      float sum = 0.f;
      #pragma unroll
      for (int j = 0; j < 8; j++) sum += vals[j];
      sum += __shfl_xor(sum, 8); sum += __shfl_xor(sum, 4);
      sum += __shfl_xor(sum, 2); sum += __shfl_xor(sum, 1);
      float mu = sum * (1.f / 128.f);
      float sq = 0.f;
      #pragma unroll
      for (int j = 0; j < 8; j++) { float d = vals[j] - mu; sq += d * d; }
      sq += __shfl_xor(sq, 8); sq += __shfl_xor(sq, 4);
      sq += __shfl_xor(sq, 2); sq += __shfl_xor(sq, 1);
      float rstd = rsqrtf(sq * (1.f / 128.f) + 1e-5f);
      #pragma unroll
      for (int j = 0; j < 8; j++)
        h8[j] = (short)f2bf((vals[j] - mu) * rstd * gv[j] + bv2[j]);
    }
    *(short8*)&lnA[nl][(gl ^ (nl & 7)) * 8] = h8;
  }
  __syncthreads();
  int w = tid >> 6, lane = tid & 63;
  int rt = w;  // each wave owns 16 node-rows
  int arow = rt * 16 + (lane & 15);
  short8 afr[4];
  #pragma unroll
  for (int kt = 0; kt < 4; kt++) {
    int chunk = (kt * 4 + (lane >> 4)) ^ (lane & 7);
    afr[kt] = *(const short8*)&lnA[arow][chunk * 8];
  }
  for (int ct = 0; ct < 32; ct++) {
    int j = ct * 16 + (lane & 15);
    f32x4 acc = {0.f, 0.f, 0.f, 0.f};
    const unsigned short* wrow = wqkvs + (size_t)j * 128 + (lane >> 4) * 8;
    #pragma unroll
    for (int kt = 0; kt < 4; kt++) {
      short8 b = *(const short8*)(wrow + kt * 32);
      acc = __builtin_amdgcn_mfma_f32_16x16x32_bf16(afr[kt], b, acc, 0, 0, 0);
    }
    int mat = j >> 7, jj = j & 127;
    const float* biasp = (mat == 0) ? bq : (mat == 1) ? bk : (mat == 2) ? bv : bs;
    float* outp = (mat == 0) ? q : (mat == 1) ? k : (mat == 2) ? v : s;
    float bj = biasp[jj];
    #pragma unroll
    for (int r = 0; r < 4; r++) {
      int node = node0 + rt * 16 + (lane >> 4) * 4 + r;
      if (node < n) outp[(size_t)node * HID + jj] = acc[r] + bj;
    }
  }
}

// -------- CSR build: count degrees ------------------------------------------
__global__ __launch_bounds__(256) void count_kernel(
    const int* __restrict__ ei, int* __restrict__ deg)
{
  int e = blockIdx.x * 256 + threadIdx.x;
  if (e < E_EDGES) atomicAdd(deg + ei[E_EDGES + e], 1);
}

// -------- CSR build: exclusive scan (single block, 1024 threads) -------------
__global__ __launch_bounds__(1024) void scan_kernel(
    const int* __restrict__ deg, int* __restrict__ row_start,
    int* __restrict__ cursor, int n)
{
  __shared__ int sums[1024];
  int tid = threadIdx.x;
  int chunk = (n + 1023) / 1024;
  int start = tid * chunk;
  int end = min(start + chunk, n);
  int s = 0;
  for (int i = start; i < end; i++) s += deg[i];
  sums[tid] = s;
  __syncthreads();
  for (int off = 1; off < 1024; off <<= 1) {
    int t = (tid >= off) ? sums[tid - off] : 0;
    __syncthreads();
    sums[tid] += t;
    __syncthreads();
  }
  int run = sums[tid] - s;
  for (int i = start; i < end; i++) {
    row_start[i] = run;
    cursor[i] = run;
    run += deg[i];
  }
}

// -------- CSR build: scatter packed (src, attr) records ----------------------
__global__ __launch_bounds__(256) void scatter_kernel(
    const int* __restrict__ ei, const float4* __restrict__ attr,
    int* __restrict__ cursor,
    int* __restrict__ csr_src, float4* __restrict__ csr_attr)
{
  int e = blockIdx.x * 256 + threadIdx.x;
  if (e >= E_EDGES) return;
  int dst = ei[E_EDGES + e];
  int pos = atomicAdd(cursor + dst, 1);
  csr_src[pos] = ei[e];
  csr_attr[pos] = attr[e];
}

// -------- Gather + combine: 1 wave per dst node, lane = 2 channels -----------
__global__ __launch_bounds__(256) void gather_kernel(
    const int* __restrict__ row_start, const int* __restrict__ deg,
    const int* __restrict__ csr_src, const float4* __restrict__ csr_attr,
    const float* __restrict__ We,
    const float* __restrict__ q, const float* __restrict__ k,
    const float* __restrict__ v,
    const float* __restrict__ x, const float* __restrict__ sk,
    const float* __restrict__ Wb, float* __restrict__ xn, int n)
{
  int node = (blockIdx.x * blockDim.x + threadIdx.x) >> 6;
  if (node >= n) return;
  int lane = threadIdx.x & 63;
  int c0 = lane * 2;
  float4 w0 = *(const float4*)(We + c0 * 4);
  float4 w1 = *(const float4*)(We + c0 * 4 + 4);
  float2 qd = *(const float2*)(q + (size_t)node * HID + c0);
  float acc0 = 0.f, acc1 = 0.f, den = 0.f;
  int rs = row_start[node];
  int re = rs + deg[node];
  for (int j = rs; j < re; j++) {
    int src = csr_src[j];
    float4 a4 = csr_attr[j];
    float e0 = a4.x * w0.x + a4.y * w0.y + a4.z * w0.z + a4.w * w0.w;
    float e1 = a4.x * w1.x + a4.y * w1.y + a4.z * w1.z + a4.w * w1.w;
    float2 ks = *(const float2*)(k + (size_t)src * HID + c0);
    float2 vs = *(const float2*)(v + (size_t)src * HID + c0);
    float kj0 = ks.x + e0, kj1 = ks.y + e1;
    float part = qd.x * kj0 + qd.y * kj1;
    part += __shfl_xor(part, 1);
    part += __shfl_xor(part, 2);
    part += __shfl_xor(part, 4);
    part += __shfl_xor(part, 8);
    float a = expf(part * 0.17677669529663687f);  // 1/sqrt(32); max-free softmax
    acc0 += a * (vs.x + e0);
    acc1 += a * (vs.y + e1);
    den += a;
  }
  float inv = 1.0f / (den + 1e-16f);
  float o0 = acc0 * inv, o1 = acc1 * inv;
  float2 skp = *(const float2*)(sk + (size_t)node * HID + c0);
  float wb_o0 = Wb[c0] + Wb[256 + c0];
  float wb_o1 = Wb[c0 + 1] + Wb[256 + c0 + 1];
  float wb_s0 = Wb[128 + c0] - Wb[256 + c0];
  float wb_s1 = Wb[128 + c0 + 1] - Wb[256 + c0 + 1];
  float bpart = o0 * wb_o0 + o1 * wb_o1 + skp.x * wb_s0 + skp.y * wb_s1;
  for (int m = 32; m >= 1; m >>= 1) bpart += __shfl_xor(bpart, m);
  float beta = 1.0f / (1.0f + expf(-bpart));
  float h0 = beta * skp.x + (1.0f - beta) * o0;
  float h1 = beta * skp.y + (1.0f - beta) * o1;
  float2 xv = *(const float2*)(x + (size_t)node * HID + c0);
  *(float2*)(xn + (size_t)node * HID + c0) = make_float2(xv.x + h0, xv.y + h1);
}

// ---- fused LN2 + MLP (GEMM1 relu GEMM2) via bf16 MFMA + residual ------------
// block: 256 thr, 32 nodes. t [32][512] bf16 in LDS, XOR-swizzled.
__global__ __launch_bounds__(256) void mlp_kernel(
    const float* __restrict__ xn,
    const float* __restrict__ g2, const float* __restrict__ b2ln,
    const unsigned short* __restrict__ w1b, const float* __restrict__ b1,
    const unsigned short* __restrict__ w2b, const float* __restrict__ b2,
    float* __restrict__ out, int n)
{
  __shared__ short lnA[32][128];
  __shared__ short tS[32][512];
  int node0 = blockIdx.x * 32;
  int tid = threadIdx.x;
  int g = tid >> 4, gl = tid & 15, c0 = gl * 8;
  {
    float gv[8], bv2[8];
    *(float4*)&gv[0] = *(const float4*)(g2 + c0);
    *(float4*)&gv[4] = *(const float4*)(g2 + c0 + 4);
    *(float4*)&bv2[0] = *(const float4*)(b2ln + c0);
    *(float4*)&bv2[4] = *(const float4*)(b2ln + c0 + 4);
    for (int ni = 0; ni < 2; ni++) {
      int nl = ni * 16 + g;
      int node = node0 + nl;
      short8 h8 = {0, 0, 0, 0, 0, 0, 0, 0};
      if (node < n) {
        float vals[8];
        const float* row = xn + (size_t)node * HID + c0;
        *(float4*)&vals[0] = *(const float4*)row;
        *(float4*)&vals[4] = *(const float4*)(row + 4);
        float sum = 0.f;
        #pragma unroll
        for (int j = 0; j < 8; j++) sum += vals[j];
        sum += __shfl_xor(sum, 8); sum += __shfl_xor(sum, 4);
        sum += __shfl_xor(sum, 2); sum += __shfl_xor(sum, 1);
        float mu = sum * (1.f / 128.f);
        float sq = 0.f;
        #pragma unroll
        for (int j = 0; j < 8; j++) { float d = vals[j] - mu; sq += d * d; }
        sq += __shfl_xor(sq, 8); sq += __shfl_xor(sq, 4);
        sq += __shfl_xor(sq, 2); sq += __shfl_xor(sq, 1);
        float rstd = rsqrtf(sq * (1.f / 128.f) + 1e-5f);
        #pragma unroll
        for (int j = 0; j < 8; j++)
          h8[j] = (short)f2bf((vals[j] - mu) * rstd * gv[j] + bv2[j]);
      }
      *(short8*)&lnA[nl][(gl ^ (nl & 7)) * 8] = h8;
    }
  }
  __syncthreads();
  int w = tid >> 6, lane = tid & 63;
  // ---- GEMM1: [32 x 128] @ W1^T -> t [32 x 512], +b1, relu, bf16 to LDS ----
  {
    int rt = w >> 1;
    int arow = rt * 16 + (lane & 15);
    short8 afr[4];
    #pragma unroll
    for (int kt = 0; kt < 4; kt++) {
      int chunk = (kt * 4 + (lane >> 4)) ^ (lane & 7);
      afr[kt] = *(const short8*)&lnA[arow][chunk * 8];
    }
    int ct0 = (w & 1) * 16;
    for (int ct = ct0; ct < ct0 + 16; ct++) {
      int j = ct * 16 + (lane & 15);
      f32x4 acc = {0.f, 0.f, 0.f, 0.f};
      const unsigned short* wrow = w1b + (size_t)j * 128 + (lane >> 4) * 8;
      #pragma unroll
      for (int kt = 0; kt < 4; kt++) {
        short8 b = *(const short8*)(wrow + kt * 32);
        acc = __builtin_amdgcn_mfma_f32_16x16x32_bf16(afr[kt], b, acc, 0, 0, 0);
      }
      float bj = b1[j];
      #pragma unroll
      for (int r = 0; r < 4; r++) {
        int nl = rt * 16 + (lane >> 4) * 4 + r;
        float tv = fmaxf(acc[r] + bj, 0.f);
        tS[nl][(((j >> 3) ^ (nl & 7)) * 8) + (j & 7)] = (short)f2bf(tv);
      }
    }
  }
  __syncthreads();
  // ---- GEMM2: t [32 x 512] @ W2^T -> [32 x 128], +b2, +xn residual ---------
  {
    int rt = w >> 1;
    int arow = rt * 16 + (lane & 15);
    short8 afr[16];
    #pragma unroll
    for (int kt = 0; kt < 16; kt++) {
      int chunk = (kt * 4 + (lane >> 4)) ^ (lane & 7);
      afr[kt] = *(const short8*)&tS[arow][chunk * 8];
    }
    int ct0 = (w & 1) * 4;
    for (int ct = ct0; ct < ct0 + 4; ct++) {
      int c = ct * 16 + (lane & 15);
      f32x4 acc = {0.f, 0.f, 0.f, 0.f};
      const unsigned short* wrow = w2b + (size_t)c * 512 + (lane >> 4) * 8;
      #pragma unroll
      for (int kt = 0; kt < 16; kt++) {
        short8 b = *(const short8*)(wrow + kt * 32);
        acc = __builtin_amdgcn_mfma_f32_16x16x32_bf16(afr[kt], b, acc, 0, 0, 0);
      }
      float bj = b2[c];
      #pragma unroll
      for (int r = 0; r < 4; r++) {
        int node = node0 + rt * 16 + (lane >> 4) * 4 + r;
        if (node < n)
          out[(size_t)node * HID + c] = xn[(size_t)node * HID + c] + acc[r] + bj;
      }
    }
  }
}

extern "C" void kernel_launch(void* const* d_in, const int* in_sizes, int n_in,
                              void* d_out, int out_size, void* d_ws, size_t ws_size,
                              hipStream_t stream) {
  const float* x     = (const float*)d_in[0];
  const int*   ei    = (const int*)d_in[1];
  const float* attr  = (const float*)d_in[2];
  const float* ln1_g = (const float*)d_in[3];
  const float* ln1_b = (const float*)d_in[4];
  const float* Wq    = (const float*)d_in[5];
  const float* bq    = (const float*)d_in[6];
  const float* Wk    = (const float*)d_in[7];
  const float* bk    = (const float*)d_in[8];
  const float* Wv    = (const float*)d_in[9];
  const float* bv    = (const float*)d_in[10];
  const float* We    = (const float*)d_in[11];
  const float* Wskip = (const float*)d_in[12];
  const float* bskip = (const float*)d_in[13];
  const float* Wbeta = (const float*)d_in[14];
  const float* ln2_g = (const float*)d_in[15];
  const float* ln2_b = (const float*)d_in[16];
  const float* W1    = (const float*)d_in[17];
  const float* b1    = (const float*)d_in[18];
  const float* W2    = (const float*)d_in[19];
  const float* b2    = (const float*)d_in[20];
  float* out = (float*)d_out;
  float* ws  = (float*)d_ws;

  size_t NH = (size_t)N_NODES * HID;  // 6.4M
  float* q  = ws;
  float* k  = ws + NH;
  float* v  = ws + 2 * NH;
  float* s  = ws + 3 * NH;
  float* xn = ws + 4 * NH;
  int* deg       = (int*)(ws + 5 * NH);
  int* row_start = deg + N_NODES;
  int* cursor    = row_start + N_NODES;
  int* csr_src   = cursor + N_NODES;
  // 3*N + E ints = 950000 (multiple of 4) -> csr_attr stays 16B-aligned
  float4* csr_attr = (float4*)(ws + 5 * NH + 950000);
  unsigned short* wqkvs = (unsigned short*)(ws + 5 * NH + 950000 + (size_t)E_EDGES * 4);
  unsigned short* w1b   = wqkvs + 65536;
  unsigned short* w2b   = w1b + 65536;

  hipMemsetAsync(deg, 0, N_NODES * sizeof(int), stream);

  wcvt_kernel<<<192, 256, 0, stream>>>(
      (const float4*)Wq, (const float4*)Wk, (const float4*)Wv,
      (const float4*)Wskip, (const float4*)W1, (const float4*)W2,
      wqkvs, w1b, w2b);
  qkvs_kernel<<<(N_NODES + 63) / 64, 256, 0, stream>>>(
      x, ln1_g, ln1_b, wqkvs, bq, bk, bv, bskip, q, k, v, s, N_NODES);
  count_kernel<<<(E_EDGES + 255) / 256, 256, 0, stream>>>(ei, deg);
  scan_kernel<<<1, 1024, 0, stream>>>(deg, row_start, cursor, N_NODES);
  scatter_kernel<<<(E_EDGES + 255) / 256, 256, 0, stream>>>(
      ei, (const float4*)attr, cursor, csr_src, csr_attr);
  gather_kernel<<<(N_NODES * 64 + 255) / 256, 256, 0, stream>>>(
      row_start, deg, csr_src, csr_attr, We, q, k, v, x, s, Wbeta, xn, N_NODES);
  mlp_kernel<<<(N_NODES + 31) / 32, 256, 0, stream>>>(
      xn, ln2_g, ln2_b, w1b, b1, w2b, b2, out, N_NODES);
}

// Round 4
// 466.286 us; speedup vs baseline: 2.6912x; 1.1044x over previous
//
#include <hip/hip_runtime.h>

#define N_NODES 50000
#define E_EDGES 800000
#define HID 128

typedef __attribute__((ext_vector_type(8))) short short8;
typedef __attribute__((ext_vector_type(4))) float f32x4;

static __device__ __forceinline__ unsigned short f2bf(float f) {
  unsigned int u = __builtin_bit_cast(unsigned int, f);
  u += 0x7fff + ((u >> 16) & 1);  // round-to-nearest-even
  return (unsigned short)(u >> 16);
}
static __device__ __forceinline__ float bf2f(unsigned short u) {
  return __builtin_bit_cast(float, (unsigned int)u << 16);
}

// ---- weight conversion fp32 -> bf16 (Wq|Wk|Wv|Wskip stacked, W1, W2) --------
__global__ __launch_bounds__(256) void wcvt_kernel(
    const float4* __restrict__ Wq, const float4* __restrict__ Wk,
    const float4* __restrict__ Wv, const float4* __restrict__ Ws,
    const float4* __restrict__ W1, const float4* __restrict__ W2,
    unsigned short* __restrict__ wqkvs, unsigned short* __restrict__ w1b,
    unsigned short* __restrict__ w2b)
{
  int i = blockIdx.x * 256 + threadIdx.x;  // [0, 49152) float4 groups
  const float4* src;
  unsigned short* dst;
  if (i < 16384) {
    int part = i >> 12;
    src = ((part == 0) ? Wq : (part == 1) ? Wk : (part == 2) ? Wv : Ws) + (i & 4095);
    dst = wqkvs + i * 4;
  } else if (i < 32768) {
    src = W1 + (i - 16384); dst = w1b + (size_t)(i - 16384) * 4;
  } else {
    src = W2 + (i - 32768); dst = w2b + (size_t)(i - 32768) * 4;
  }
  float4 v = *src;
  ushort4 o;
  o.x = f2bf(v.x); o.y = f2bf(v.y); o.z = f2bf(v.z); o.w = f2bf(v.w);
  *(ushort4*)dst = o;
}

// ---- fused LN1 + QKVS projection via bf16 MFMA ------------------------------
// block: 256 thr, 64 nodes. wave w owns matrix w (128 cols) x 4 row-tiles.
// k,v written as bf16; q,s as fp32.
__global__ __launch_bounds__(256) void qkvs_kernel(
    const float* __restrict__ x,
    const float* __restrict__ g1, const float* __restrict__ bln,
    const unsigned short* __restrict__ wqkvs,
    const float* __restrict__ bq, const float* __restrict__ bk,
    const float* __restrict__ bv, const float* __restrict__ bs,
    float* __restrict__ q, unsigned short* __restrict__ kb,
    unsigned short* __restrict__ vb, float* __restrict__ s, int n)
{
  __shared__ short lnA[64][128];
  int node0 = blockIdx.x * 64;
  int tid = threadIdx.x;
  int g = tid >> 4, gl = tid & 15, c0 = gl * 8;
  {
    float gv[8], bv2[8];
    *(float4*)&gv[0] = *(const float4*)(g1 + c0);
    *(float4*)&gv[4] = *(const float4*)(g1 + c0 + 4);
    *(float4*)&bv2[0] = *(const float4*)(bln + c0);
    *(float4*)&bv2[4] = *(const float4*)(bln + c0 + 4);
    for (int ni = 0; ni < 4; ni++) {
      int nl = ni * 16 + g;
      int node = node0 + nl;
      short8 h8 = {0, 0, 0, 0, 0, 0, 0, 0};
      if (node < n) {
        float vals[8];
        const float* row = x + (size_t)node * HID + c0;
        *(float4*)&vals[0] = *(const float4*)row;
        *(float4*)&vals[4] = *(const float4*)(row + 4);
        float sum = 0.f;
        #pragma unroll
        for (int j = 0; j < 8; j++) sum += vals[j];
        sum += __shfl_xor(sum, 8); sum += __shfl_xor(sum, 4);
        sum += __shfl_xor(sum, 2); sum += __shfl_xor(sum, 1);
        float mu = sum * (1.f / 128.f);
        float sq = 0.f;
        #pragma unroll
        for (int j = 0; j < 8; j++) { float d = vals[j] - mu; sq += d * d; }
        sq += __shfl_xor(sq, 8); sq += __shfl_xor(sq, 4);
        sq += __shfl_xor(sq, 2); sq += __shfl_xor(sq, 1);
        float rstd = rsqrtf(sq * (1.f / 128.f) + 1e-5f);
        #pragma unroll
        for (int j = 0; j < 8; j++)
          h8[j] = (short)f2bf((vals[j] - mu) * rstd * gv[j] + bv2[j]);
      }
      *(short8*)&lnA[nl][(gl ^ (nl & 7)) * 8] = h8;
    }
  }
  __syncthreads();
  int w = tid >> 6, lane = tid & 63;
  int lg = lane >> 4, ll = lane & 15;
  short8 afr[4][4];
  #pragma unroll
  for (int rt = 0; rt < 4; rt++) {
    int arow = rt * 16 + ll;
    #pragma unroll
    for (int kt = 0; kt < 4; kt++)
      afr[rt][kt] = *(const short8*)&lnA[arow][((kt * 4 + lg) ^ (ll & 7)) * 8];
  }
  const float* biasp = (w == 0) ? bq : (w == 1) ? bk : (w == 2) ? bv : bs;
  for (int ci = 0; ci < 8; ci++) {
    int j = (w * 8 + ci) * 16 + ll;  // global col in [w*128, w*128+128)
    int jj = j & 127;
    const unsigned short* wrow = wqkvs + (size_t)j * 128 + lg * 8;
    short8 bfr[4];
    #pragma unroll
    for (int kt = 0; kt < 4; kt++) bfr[kt] = *(const short8*)(wrow + kt * 32);
    f32x4 acc[4];
    #pragma unroll
    for (int rt = 0; rt < 4; rt++) acc[rt] = (f32x4){0.f, 0.f, 0.f, 0.f};
    #pragma unroll
    for (int kt = 0; kt < 4; kt++)
      #pragma unroll
      for (int rt = 0; rt < 4; rt++)
        acc[rt] = __builtin_amdgcn_mfma_f32_16x16x32_bf16(afr[rt][kt], bfr[kt], acc[rt], 0, 0, 0);
    float bj = biasp[jj];
    #pragma unroll
    for (int rt = 0; rt < 4; rt++)
      #pragma unroll
      for (int r = 0; r < 4; r++) {
        int node = node0 + rt * 16 + lg * 4 + r;
        if (node < n) {
          float val = acc[rt][r] + bj;
          size_t off = (size_t)node * HID + jj;
          if (w == 0) q[off] = val;
          else if (w == 1) kb[off] = f2bf(val);
          else if (w == 2) vb[off] = f2bf(val);
          else s[off] = val;
        }
      }
  }
}

// -------- CSR build: count degrees ------------------------------------------
__global__ __launch_bounds__(256) void count_kernel(
    const int* __restrict__ ei, int* __restrict__ deg)
{
  int e = blockIdx.x * 256 + threadIdx.x;
  if (e < E_EDGES) atomicAdd(deg + ei[E_EDGES + e], 1);
}

// -------- CSR build: exclusive scan (single block, 1024 threads) -------------
__global__ __launch_bounds__(1024) void scan_kernel(
    const int* __restrict__ deg, int* __restrict__ row_start,
    int* __restrict__ cursor, int n)
{
  __shared__ int sums[1024];
  int tid = threadIdx.x;
  int chunk = (n + 1023) / 1024;
  int start = tid * chunk;
  int end = min(start + chunk, n);
  int s = 0;
  for (int i = start; i < end; i++) s += deg[i];
  sums[tid] = s;
  __syncthreads();
  for (int off = 1; off < 1024; off <<= 1) {
    int t = (tid >= off) ? sums[tid - off] : 0;
    __syncthreads();
    sums[tid] += t;
    __syncthreads();
  }
  int run = sums[tid] - s;
  for (int i = start; i < end; i++) {
    row_start[i] = run;
    cursor[i] = run;
    run += deg[i];
  }
}

// -------- CSR build: scatter packed (src, attr) records ----------------------
__global__ __launch_bounds__(256) void scatter_kernel(
    const int* __restrict__ ei, const float4* __restrict__ attr,
    int* __restrict__ cursor,
    int* __restrict__ csr_src, float4* __restrict__ csr_attr)
{
  int e = blockIdx.x * 256 + threadIdx.x;
  if (e >= E_EDGES) return;
  int dst = ei[E_EDGES + e];
  int pos = atomicAdd(cursor + dst, 1);
  csr_src[pos] = ei[e];
  csr_attr[pos] = attr[e];
}

// -------- Gather + combine: 1 wave per dst node, lane = 2 channels -----------
__global__ __launch_bounds__(256) void gather_kernel(
    const int* __restrict__ row_start, const int* __restrict__ deg,
    const int* __restrict__ csr_src, const float4* __restrict__ csr_attr,
    const float* __restrict__ We,
    const float* __restrict__ q, const unsigned short* __restrict__ kb,
    const unsigned short* __restrict__ vb,
    const float* __restrict__ x, const float* __restrict__ sk,
    const float* __restrict__ Wb, float* __restrict__ xn, int n)
{
  int node = (blockIdx.x * blockDim.x + threadIdx.x) >> 6;
  if (node >= n) return;
  int lane = threadIdx.x & 63;
  int c0 = lane * 2;
  float4 w0 = *(const float4*)(We + c0 * 4);
  float4 w1 = *(const float4*)(We + c0 * 4 + 4);
  float2 qd = *(const float2*)(q + (size_t)node * HID + c0);
  float acc0 = 0.f, acc1 = 0.f, den = 0.f;
  int rs = row_start[node];
  int re = rs + deg[node];
  for (int j = rs; j < re; j++) {
    int src = csr_src[j];
    float4 a4 = csr_attr[j];
    float e0 = a4.x * w0.x + a4.y * w0.y + a4.z * w0.z + a4.w * w0.w;
    float e1 = a4.x * w1.x + a4.y * w1.y + a4.z * w1.z + a4.w * w1.w;
    ushort2 k2 = *(const ushort2*)(kb + (size_t)src * HID + c0);
    ushort2 v2 = *(const ushort2*)(vb + (size_t)src * HID + c0);
    float kj0 = bf2f(k2.x) + e0, kj1 = bf2f(k2.y) + e1;
    float part = qd.x * kj0 + qd.y * kj1;
    part += __shfl_xor(part, 1);
    part += __shfl_xor(part, 2);
    part += __shfl_xor(part, 4);
    part += __shfl_xor(part, 8);
    float a = expf(part * 0.17677669529663687f);  // 1/sqrt(32); max-free softmax
    acc0 += a * (bf2f(v2.x) + e0);
    acc1 += a * (bf2f(v2.y) + e1);
    den += a;
  }
  float inv = 1.0f / (den + 1e-16f);
  float o0 = acc0 * inv, o1 = acc1 * inv;
  float2 skp = *(const float2*)(sk + (size_t)node * HID + c0);
  float wb_o0 = Wb[c0] + Wb[256 + c0];
  float wb_o1 = Wb[c0 + 1] + Wb[256 + c0 + 1];
  float wb_s0 = Wb[128 + c0] - Wb[256 + c0];
  float wb_s1 = Wb[128 + c0 + 1] - Wb[256 + c0 + 1];
  float bpart = o0 * wb_o0 + o1 * wb_o1 + skp.x * wb_s0 + skp.y * wb_s1;
  for (int m = 32; m >= 1; m >>= 1) bpart += __shfl_xor(bpart, m);
  float beta = 1.0f / (1.0f + expf(-bpart));
  float h0 = beta * skp.x + (1.0f - beta) * o0;
  float h1 = beta * skp.y + (1.0f - beta) * o1;
  float2 xv = *(const float2*)(x + (size_t)node * HID + c0);
  *(float2*)(xn + (size_t)node * HID + c0) = make_float2(xv.x + h0, xv.y + h1);
}

// ---- fused LN2 + MLP (GEMM1 relu GEMM2) via bf16 MFMA + residual ------------
// block: 256 thr, 32 nodes. wave w owns a col-quarter across both row-tiles.
__global__ __launch_bounds__(256) void mlp_kernel(
    const float* __restrict__ xn,
    const float* __restrict__ g2, const float* __restrict__ b2ln,
    const unsigned short* __restrict__ w1b, const float* __restrict__ b1,
    const unsigned short* __restrict__ w2b, const float* __restrict__ b2,
    float* __restrict__ out, int n)
{
  __shared__ short lnA[32][128];
  __shared__ short tS[32][512];
  int node0 = blockIdx.x * 32;
  int tid = threadIdx.x;
  int g = tid >> 4, gl = tid & 15, c0 = gl * 8;
  {
    float gv[8], bv2[8];
    *(float4*)&gv[0] = *(const float4*)(g2 + c0);
    *(float4*)&gv[4] = *(const float4*)(g2 + c0 + 4);
    *(float4*)&bv2[0] = *(const float4*)(b2ln + c0);
    *(float4*)&bv2[4] = *(const float4*)(b2ln + c0 + 4);
    for (int ni = 0; ni < 2; ni++) {
      int nl = ni * 16 + g;
      int node = node0 + nl;
      short8 h8 = {0, 0, 0, 0, 0, 0, 0, 0};
      if (node < n) {
        float vals[8];
        const float* row = xn + (size_t)node * HID + c0;
        *(float4*)&vals[0] = *(const float4*)row;
        *(float4*)&vals[4] = *(const float4*)(row + 4);
        float sum = 0.f;
        #pragma unroll
        for (int j = 0; j < 8; j++) sum += vals[j];
        sum += __shfl_xor(sum, 8); sum += __shfl_xor(sum, 4);
        sum += __shfl_xor(sum, 2); sum += __shfl_xor(sum, 1);
        float mu = sum * (1.f / 128.f);
        float sq = 0.f;
        #pragma unroll
        for (int j = 0; j < 8; j++) { float d = vals[j] - mu; sq += d * d; }
        sq += __shfl_xor(sq, 8); sq += __shfl_xor(sq, 4);
        sq += __shfl_xor(sq, 2); sq += __shfl_xor(sq, 1);
        float rstd = rsqrtf(sq * (1.f / 128.f) + 1e-5f);
        #pragma unroll
        for (int j = 0; j < 8; j++)
          h8[j] = (short)f2bf((vals[j] - mu) * rstd * gv[j] + bv2[j]);
      }
      *(short8*)&lnA[nl][(gl ^ (nl & 7)) * 8] = h8;
    }
  }
  __syncthreads();
  int w = tid >> 6, lane = tid & 63;
  int lg = lane >> 4, ll = lane & 15;
  // ---- GEMM1: [32 x 128] @ W1^T -> t [32 x 512], +b1, relu, bf16 to LDS ----
  {
    short8 afr[2][4];
    #pragma unroll
    for (int rt = 0; rt < 2; rt++) {
      int arow = rt * 16 + ll;
      #pragma unroll
      for (int kt = 0; kt < 4; kt++)
        afr[rt][kt] = *(const short8*)&lnA[arow][((kt * 4 + lg) ^ (ll & 7)) * 8];
    }
    for (int ci = 0; ci < 8; ci++) {
      int j = (w * 8 + ci) * 16 + ll;
      const unsigned short* wrow = w1b + (size_t)j * 128 + lg * 8;
      short8 bfr[4];
      #pragma unroll
      for (int kt = 0; kt < 4; kt++) bfr[kt] = *(const short8*)(wrow + kt * 32);
      f32x4 acc[2];
      acc[0] = (f32x4){0.f, 0.f, 0.f, 0.f};
      acc[1] = (f32x4){0.f, 0.f, 0.f, 0.f};
      #pragma unroll
      for (int kt = 0; kt < 4; kt++) {
        acc[0] = __builtin_amdgcn_mfma_f32_16x16x32_bf16(afr[0][kt], bfr[kt], acc[0], 0, 0, 0);
        acc[1] = __builtin_amdgcn_mfma_f32_16x16x32_bf16(afr[1][kt], bfr[kt], acc[1], 0, 0, 0);
      }
      float bj = b1[j];
      #pragma unroll
      for (int rt = 0; rt < 2; rt++)
        #pragma unroll
        for (int r = 0; r < 4; r++) {
          int nl = rt * 16 + lg * 4 + r;
          float tv = fmaxf(acc[rt][r] + bj, 0.f);
          tS[nl][(((j >> 3) ^ (nl & 7)) * 8) + (j & 7)] = (short)f2bf(tv);
        }
    }
  }
  __syncthreads();
  // ---- GEMM2: t [32 x 512] @ W2^T -> [32 x 128], +b2, +xn residual ---------
  {
    for (int ci = 0; ci < 2; ci++) {
      int c = (w * 2 + ci) * 16 + ll;
      const unsigned short* wrow = w2b + (size_t)c * 512 + lg * 8;
      short8 bfr[16];
      #pragma unroll
      for (int kt = 0; kt < 16; kt++) bfr[kt] = *(const short8*)(wrow + kt * 32);
      float bj = b2[c];
      #pragma unroll
      for (int rt = 0; rt < 2; rt++) {
        int arow = rt * 16 + ll;
        f32x4 acc = {0.f, 0.f, 0.f, 0.f};
        #pragma unroll
        for (int kt = 0; kt < 16; kt++) {
          short8 a = *(const short8*)&tS[arow][((kt * 4 + lg) ^ (ll & 7)) * 8];
          acc = __builtin_amdgcn_mfma_f32_16x16x32_bf16(a, bfr[kt], acc, 0, 0, 0);
        }
        #pragma unroll
        for (int r = 0; r < 4; r++) {
          int node = node0 + rt * 16 + lg * 4 + r;
          if (node < n)
            out[(size_t)node * HID + c] = xn[(size_t)node * HID + c] + acc[r] + bj;
        }
      }
    }
  }
}

extern "C" void kernel_launch(void* const* d_in, const int* in_sizes, int n_in,
                              void* d_out, int out_size, void* d_ws, size_t ws_size,
                              hipStream_t stream) {
  const float* x     = (const float*)d_in[0];
  const int*   ei    = (const int*)d_in[1];
  const float* attr  = (const float*)d_in[2];
  const float* ln1_g = (const float*)d_in[3];
  const float* ln1_b = (const float*)d_in[4];
  const float* Wq    = (const float*)d_in[5];
  const float* bq    = (const float*)d_in[6];
  const float* Wk    = (const float*)d_in[7];
  const float* bk    = (const float*)d_in[8];
  const float* Wv    = (const float*)d_in[9];
  const float* bv    = (const float*)d_in[10];
  const float* We    = (const float*)d_in[11];
  const float* Wskip = (const float*)d_in[12];
  const float* bskip = (const float*)d_in[13];
  const float* Wbeta = (const float*)d_in[14];
  const float* ln2_g = (const float*)d_in[15];
  const float* ln2_b = (const float*)d_in[16];
  const float* W1    = (const float*)d_in[17];
  const float* b1    = (const float*)d_in[18];
  const float* W2    = (const float*)d_in[19];
  const float* b2    = (const float*)d_in[20];
  float* out = (float*)d_out;
  float* ws  = (float*)d_ws;

  size_t NH = (size_t)N_NODES * HID;  // 6.4M
  float* q  = ws;
  float* s  = ws + NH;
  float* xn = ws + 2 * NH;
  unsigned short* kb = (unsigned short*)(ws + 3 * NH);           // NH ushorts
  unsigned short* vb = (unsigned short*)(ws + 3 * NH) + NH;
  int* deg       = (int*)(ws + 4 * NH);
  int* row_start = deg + N_NODES;
  int* cursor    = row_start + N_NODES;
  int* csr_src   = cursor + N_NODES;
  // 3*N + E ints = 950000 (multiple of 4) -> csr_attr stays 16B-aligned
  float4* csr_attr = (float4*)(ws + 4 * NH + 950000);
  unsigned short* wqkvs = (unsigned short*)(ws + 4 * NH + 950000 + (size_t)E_EDGES * 4);
  unsigned short* w1b   = wqkvs + 65536;
  unsigned short* w2b   = w1b + 65536;

  hipMemsetAsync(deg, 0, N_NODES * sizeof(int), stream);

  wcvt_kernel<<<192, 256, 0, stream>>>(
      (const float4*)Wq, (const float4*)Wk, (const float4*)Wv,
      (const float4*)Wskip, (const float4*)W1, (const float4*)W2,
      wqkvs, w1b, w2b);
  qkvs_kernel<<<(N_NODES + 63) / 64, 256, 0, stream>>>(
      x, ln1_g, ln1_b, wqkvs, bq, bk, bv, bskip, q, kb, vb, s, N_NODES);
  count_kernel<<<(E_EDGES + 255) / 256, 256, 0, stream>>>(ei, deg);
  scan_kernel<<<1, 1024, 0, stream>>>(deg, row_start, cursor, N_NODES);
  scatter_kernel<<<(E_EDGES + 255) / 256, 256, 0, stream>>>(
      ei, (const float4*)attr, cursor, csr_src, csr_attr);
  gather_kernel<<<(N_NODES * 64 + 255) / 256, 256, 0, stream>>>(
      row_start, deg, csr_src, csr_attr, We, q, kb, vb, x, s, Wbeta, xn, N_NODES);
  mlp_kernel<<<(N_NODES + 31) / 32, 256, 0, stream>>>(
      xn, ln2_g, ln2_b, w1b, b1, w2b, b2, out, N_NODES);
}

// Round 5
// 462.193 us; speedup vs baseline: 2.7150x; 1.0089x over previous
//
#include <hip/hip_runtime.h>

#define N_NODES 50000
#define E_EDGES 800000
#define HID 128

typedef __attribute__((ext_vector_type(8))) short short8;
typedef __attribute__((ext_vector_type(4))) float f32x4;

static __device__ __forceinline__ unsigned short f2bf(float f) {
  unsigned int u = __builtin_bit_cast(unsigned int, f);
  u += 0x7fff + ((u >> 16) & 1);  // round-to-nearest-even
  return (unsigned short)(u >> 16);
}
static __device__ __forceinline__ float bf2f(unsigned short u) {
  return __builtin_bit_cast(float, (unsigned int)u << 16);
}

// ---- weight conversion fp32 -> bf16 (Wq|Wk|Wv|Wskip stacked, W1, W2) --------
__global__ __launch_bounds__(256) void wcvt_kernel(
    const float4* __restrict__ Wq, const float4* __restrict__ Wk,
    const float4* __restrict__ Wv, const float4* __restrict__ Ws,
    const float4* __restrict__ W1, const float4* __restrict__ W2,
    unsigned short* __restrict__ wqkvs, unsigned short* __restrict__ w1b,
    unsigned short* __restrict__ w2b)
{
  int i = blockIdx.x * 256 + threadIdx.x;  // [0, 49152) float4 groups
  const float4* src;
  unsigned short* dst;
  if (i < 16384) {
    int part = i >> 12;
    src = ((part == 0) ? Wq : (part == 1) ? Wk : (part == 2) ? Wv : Ws) + (i & 4095);
    dst = wqkvs + i * 4;
  } else if (i < 32768) {
    src = W1 + (i - 16384); dst = w1b + (size_t)(i - 16384) * 4;
  } else {
    src = W2 + (i - 32768); dst = w2b + (size_t)(i - 32768) * 4;
  }
  float4 v = *src;
  ushort4 o;
  o.x = f2bf(v.x); o.y = f2bf(v.y); o.z = f2bf(v.z); o.w = f2bf(v.w);
  *(ushort4*)dst = o;
}

// ---- fused LN1 + QKVS projection via bf16 MFMA ------------------------------
// block: 256 thr, 64 nodes. wave w owns matrix w (128 cols) x 4 row-tiles.
// k,v written as bf16 into packed kv[node][256]; q,s as fp32.
__global__ __launch_bounds__(256) void qkvs_kernel(
    const float* __restrict__ x,
    const float* __restrict__ g1, const float* __restrict__ bln,
    const unsigned short* __restrict__ wqkvs,
    const float* __restrict__ bq, const float* __restrict__ bk,
    const float* __restrict__ bv, const float* __restrict__ bs,
    float* __restrict__ q, unsigned short* __restrict__ kvb,
    float* __restrict__ s, int n)
{
  __shared__ short lnA[64][128];
  int node0 = blockIdx.x * 64;
  int tid = threadIdx.x;
  int g = tid >> 4, gl = tid & 15, c0 = gl * 8;
  {
    float gv[8], bv2[8];
    *(float4*)&gv[0] = *(const float4*)(g1 + c0);
    *(float4*)&gv[4] = *(const float4*)(g1 + c0 + 4);
    *(float4*)&bv2[0] = *(const float4*)(bln + c0);
    *(float4*)&bv2[4] = *(const float4*)(bln + c0 + 4);
    for (int ni = 0; ni < 4; ni++) {
      int nl = ni * 16 + g;
      int node = node0 + nl;
      short8 h8 = {0, 0, 0, 0, 0, 0, 0, 0};
      if (node < n) {
        float vals[8];
        const float* row = x + (size_t)node * HID + c0;
        *(float4*)&vals[0] = *(const float4*)row;
        *(float4*)&vals[4] = *(const float4*)(row + 4);
        float sum = 0.f;
        #pragma unroll
        for (int j = 0; j < 8; j++) sum += vals[j];
        sum += __shfl_xor(sum, 8); sum += __shfl_xor(sum, 4);
        sum += __shfl_xor(sum, 2); sum += __shfl_xor(sum, 1);
        float mu = sum * (1.f / 128.f);
        float sq = 0.f;
        #pragma unroll
        for (int j = 0; j < 8; j++) { float d = vals[j] - mu; sq += d * d; }
        sq += __shfl_xor(sq, 8); sq += __shfl_xor(sq, 4);
        sq += __shfl_xor(sq, 2); sq += __shfl_xor(sq, 1);
        float rstd = rsqrtf(sq * (1.f / 128.f) + 1e-5f);
        #pragma unroll
        for (int j = 0; j < 8; j++)
          h8[j] = (short)f2bf((vals[j] - mu) * rstd * gv[j] + bv2[j]);
      }
      *(short8*)&lnA[nl][(gl ^ (nl & 7)) * 8] = h8;
    }
  }
  __syncthreads();
  int w = tid >> 6, lane = tid & 63;
  int lg = lane >> 4, ll = lane & 15;
  short8 afr[4][4];
  #pragma unroll
  for (int rt = 0; rt < 4; rt++) {
    int arow = rt * 16 + ll;
    #pragma unroll
    for (int kt = 0; kt < 4; kt++)
      afr[rt][kt] = *(const short8*)&lnA[arow][((kt * 4 + lg) ^ (ll & 7)) * 8];
  }
  const float* biasp = (w == 0) ? bq : (w == 1) ? bk : (w == 2) ? bv : bs;
  for (int ci = 0; ci < 8; ci++) {
    int j = (w * 8 + ci) * 16 + ll;  // global col in [w*128, w*128+128)
    int jj = j & 127;
    const unsigned short* wrow = wqkvs + (size_t)j * 128 + lg * 8;
    short8 bfr[4];
    #pragma unroll
    for (int kt = 0; kt < 4; kt++) bfr[kt] = *(const short8*)(wrow + kt * 32);
    f32x4 acc[4];
    #pragma unroll
    for (int rt = 0; rt < 4; rt++) acc[rt] = (f32x4){0.f, 0.f, 0.f, 0.f};
    #pragma unroll
    for (int kt = 0; kt < 4; kt++)
      #pragma unroll
      for (int rt = 0; rt < 4; rt++)
        acc[rt] = __builtin_amdgcn_mfma_f32_16x16x32_bf16(afr[rt][kt], bfr[kt], acc[rt], 0, 0, 0);
    float bj = biasp[jj];
    #pragma unroll
    for (int rt = 0; rt < 4; rt++)
      #pragma unroll
      for (int r = 0; r < 4; r++) {
        int node = node0 + rt * 16 + lg * 4 + r;
        if (node < n) {
          float val = acc[rt][r] + bj;
          if (w == 0) q[(size_t)node * HID + jj] = val;
          else if (w == 1) kvb[(size_t)node * 256 + jj] = f2bf(val);
          else if (w == 2) kvb[(size_t)node * 256 + 128 + jj] = f2bf(val);
          else s[(size_t)node * HID + jj] = val;
        }
      }
  }
}

// -------- CSR build: count degrees ------------------------------------------
__global__ __launch_bounds__(256) void count_kernel(
    const int* __restrict__ ei, int* __restrict__ deg)
{
  int e = blockIdx.x * 256 + threadIdx.x;
  if (e < E_EDGES) atomicAdd(deg + ei[E_EDGES + e], 1);
}

// -------- CSR build: exclusive scan (single block, 1024 threads) -------------
__global__ __launch_bounds__(1024) void scan_kernel(
    const int* __restrict__ deg, int* __restrict__ row_start,
    int* __restrict__ cursor, int n)
{
  __shared__ int sums[1024];
  int tid = threadIdx.x;
  int chunk = (n + 1023) / 1024;
  int start = tid * chunk;
  int end = min(start + chunk, n);
  int s = 0;
  for (int i = start; i < end; i++) s += deg[i];
  sums[tid] = s;
  __syncthreads();
  for (int off = 1; off < 1024; off <<= 1) {
    int t = (tid >= off) ? sums[tid - off] : 0;
    __syncthreads();
    sums[tid] += t;
    __syncthreads();
  }
  int run = sums[tid] - s;
  for (int i = start; i < end; i++) {
    row_start[i] = run;
    cursor[i] = run;
    run += deg[i];
  }
}

// -------- CSR build: scatter packed (src, attr) records ----------------------
__global__ __launch_bounds__(256) void scatter_kernel(
    const int* __restrict__ ei, const float4* __restrict__ attr,
    int* __restrict__ cursor,
    int* __restrict__ csr_src, float4* __restrict__ csr_attr)
{
  int e = blockIdx.x * 256 + threadIdx.x;
  if (e >= E_EDGES) return;
  int dst = ei[E_EDGES + e];
  int pos = atomicAdd(cursor + dst, 1);
  csr_src[pos] = ei[e];
  csr_attr[pos] = attr[e];
}

// -------- Gather + combine: 1 wave per dst node, 4 edge slots x 16 lanes -----
// lane: g = lane>>4 (edge slot), wl = lane&15 (8 channels), head = wl>>2.
// Uses q·(k+e) = q·k + (q^T We)·attr  and  Σ a_j e_j = We (Σ a_j attr_j).
__global__ __launch_bounds__(256) void gather_kernel(
    const int* __restrict__ row_start, const int* __restrict__ deg,
    const int* __restrict__ csr_src, const float4* __restrict__ csr_attr,
    const float* __restrict__ We,
    const float* __restrict__ q, const unsigned short* __restrict__ kvb,
    const float* __restrict__ x, const float* __restrict__ sk,
    const float* __restrict__ Wb, float* __restrict__ xn, int n)
{
  int node = (blockIdx.x * blockDim.x + threadIdx.x) >> 6;
  if (node >= n) return;
  int lane = threadIdx.x & 63;
  int g = lane >> 4;
  int wl = lane & 15;
  int c0 = wl * 8;
  float q8[8];
  *(float4*)&q8[0] = *(const float4*)(q + (size_t)node * HID + c0);
  *(float4*)&q8[4] = *(const float4*)(q + (size_t)node * HID + c0 + 4);
  // qWe[4] for this head (reduce over the head's 4 lanes)
  float qwe[4] = {0.f, 0.f, 0.f, 0.f};
  #pragma unroll
  for (int i = 0; i < 8; i++) {
    float4 wr = *(const float4*)(We + (c0 + i) * 4);
    qwe[0] += q8[i] * wr.x; qwe[1] += q8[i] * wr.y;
    qwe[2] += q8[i] * wr.z; qwe[3] += q8[i] * wr.w;
  }
  #pragma unroll
  for (int t = 0; t < 4; t++) {
    qwe[t] += __shfl_xor(qwe[t], 1);
    qwe[t] += __shfl_xor(qwe[t], 2);
  }
  float acc[8] = {0.f, 0.f, 0.f, 0.f, 0.f, 0.f, 0.f, 0.f};
  float aat[4] = {0.f, 0.f, 0.f, 0.f};
  float den = 0.f;
  int rs = row_start[node];
  int re = rs + deg[node];
  const float s2 = 0.17677669529663687f * 1.4426950408889634f;  // /sqrt(32)*log2e
  for (int j = rs + g; j < re; j += 4) {
    int src = csr_src[j];
    float4 a4 = csr_attr[j];
    const unsigned short* kvrow = kvb + (size_t)src * 256 + c0;
    short8 k8 = *(const short8*)kvrow;
    short8 v8 = *(const short8*)(kvrow + 128);
    float dot = 0.f;
    #pragma unroll
    for (int i = 0; i < 8; i++) dot += q8[i] * bf2f((unsigned short)k8[i]);
    dot += __shfl_xor(dot, 1);
    dot += __shfl_xor(dot, 2);
    float a = exp2f((dot + qwe[0] * a4.x + qwe[1] * a4.y +
                     qwe[2] * a4.z + qwe[3] * a4.w) * s2);  // max-free softmax
    den += a;
    aat[0] += a * a4.x; aat[1] += a * a4.y;
    aat[2] += a * a4.z; aat[3] += a * a4.w;
    #pragma unroll
    for (int i = 0; i < 8; i++) acc[i] += a * bf2f((unsigned short)v8[i]);
  }
  // combine the 4 edge slots (lanes ^16, ^32 hold same channels)
  #pragma unroll
  for (int i = 0; i < 8; i++) {
    acc[i] += __shfl_xor(acc[i], 16);
    acc[i] += __shfl_xor(acc[i], 32);
  }
  den += __shfl_xor(den, 16); den += __shfl_xor(den, 32);
  #pragma unroll
  for (int t = 0; t < 4; t++) {
    aat[t] += __shfl_xor(aat[t], 16);
    aat[t] += __shfl_xor(aat[t], 32);
  }
  float inv = 1.0f / (den + 1e-16f);
  float o8[8];
  #pragma unroll
  for (int i = 0; i < 8; i++) {
    float4 wr = *(const float4*)(We + (c0 + i) * 4);
    o8[i] = (acc[i] + wr.x * aat[0] + wr.y * aat[1] +
             wr.z * aat[2] + wr.w * aat[3]) * inv;
  }
  float sk8[8];
  *(float4*)&sk8[0] = *(const float4*)(sk + (size_t)node * HID + c0);
  *(float4*)&sk8[4] = *(const float4*)(sk + (size_t)node * HID + c0 + 4);
  float bpart = 0.f;
  #pragma unroll
  for (int i = 0; i < 8; i++) {
    int c = c0 + i;
    bpart += o8[i] * (Wb[c] + Wb[256 + c]) + sk8[i] * (Wb[128 + c] - Wb[256 + c]);
  }
  bpart += __shfl_xor(bpart, 1); bpart += __shfl_xor(bpart, 2);
  bpart += __shfl_xor(bpart, 4); bpart += __shfl_xor(bpart, 8);
  float beta = 1.0f / (1.0f + exp2f(-bpart * 1.4426950408889634f));
  if (g == 0) {
    float xv8[8], r8[8];
    *(float4*)&xv8[0] = *(const float4*)(x + (size_t)node * HID + c0);
    *(float4*)&xv8[4] = *(const float4*)(x + (size_t)node * HID + c0 + 4);
    #pragma unroll
    for (int i = 0; i < 8; i++)
      r8[i] = xv8[i] + beta * sk8[i] + (1.0f - beta) * o8[i];
    *(float4*)(xn + (size_t)node * HID + c0) = *(float4*)&r8[0];
    *(float4*)(xn + (size_t)node * HID + c0 + 4) = *(float4*)&r8[4];
  }
}

// ---- fused LN2 + MLP (GEMM1 relu GEMM2) via bf16 MFMA + residual ------------
// block: 256 thr, 32 nodes. wave w owns a col-quarter across both row-tiles.
__global__ __launch_bounds__(256) void mlp_kernel(
    const float* __restrict__ xn,
    const float* __restrict__ g2, const float* __restrict__ b2ln,
    const unsigned short* __restrict__ w1b, const float* __restrict__ b1,
    const unsigned short* __restrict__ w2b, const float* __restrict__ b2,
    float* __restrict__ out, int n)
{
  __shared__ short lnA[32][128];
  __shared__ short tS[32][512];
  int node0 = blockIdx.x * 32;
  int tid = threadIdx.x;
  int g = tid >> 4, gl = tid & 15, c0 = gl * 8;
  {
    float gv[8], bv2[8];
    *(float4*)&gv[0] = *(const float4*)(g2 + c0);
    *(float4*)&gv[4] = *(const float4*)(g2 + c0 + 4);
    *(float4*)&bv2[0] = *(const float4*)(b2ln + c0);
    *(float4*)&bv2[4] = *(const float4*)(b2ln + c0 + 4);
    for (int ni = 0; ni < 2; ni++) {
      int nl = ni * 16 + g;
      int node = node0 + nl;
      short8 h8 = {0, 0, 0, 0, 0, 0, 0, 0};
      if (node < n) {
        float vals[8];
        const float* row = xn + (size_t)node * HID + c0;
        *(float4*)&vals[0] = *(const float4*)row;
        *(float4*)&vals[4] = *(const float4*)(row + 4);
        float sum = 0.f;
        #pragma unroll
        for (int j = 0; j < 8; j++) sum += vals[j];
        sum += __shfl_xor(sum, 8); sum += __shfl_xor(sum, 4);
        sum += __shfl_xor(sum, 2); sum += __shfl_xor(sum, 1);
        float mu = sum * (1.f / 128.f);
        float sq = 0.f;
        #pragma unroll
        for (int j = 0; j < 8; j++) { float d = vals[j] - mu; sq += d * d; }
        sq += __shfl_xor(sq, 8); sq += __shfl_xor(sq, 4);
        sq += __shfl_xor(sq, 2); sq += __shfl_xor(sq, 1);
        float rstd = rsqrtf(sq * (1.f / 128.f) + 1e-5f);
        #pragma unroll
        for (int j = 0; j < 8; j++)
          h8[j] = (short)f2bf((vals[j] - mu) * rstd * gv[j] + bv2[j]);
      }
      *(short8*)&lnA[nl][(gl ^ (nl & 7)) * 8] = h8;
    }
  }
  __syncthreads();
  int w = tid >> 6, lane = tid & 63;
  int lg = lane >> 4, ll = lane & 15;
  // ---- GEMM1: [32 x 128] @ W1^T -> t [32 x 512], +b1, relu, bf16 to LDS ----
  {
    short8 afr[2][4];
    #pragma unroll
    for (int rt = 0; rt < 2; rt++) {
      int arow = rt * 16 + ll;
      #pragma unroll
      for (int kt = 0; kt < 4; kt++)
        afr[rt][kt] = *(const short8*)&lnA[arow][((kt * 4 + lg) ^ (ll & 7)) * 8];
    }
    for (int ci = 0; ci < 8; ci++) {
      int j = (w * 8 + ci) * 16 + ll;
      const unsigned short* wrow = w1b + (size_t)j * 128 + lg * 8;
      short8 bfr[4];
      #pragma unroll
      for (int kt = 0; kt < 4; kt++) bfr[kt] = *(const short8*)(wrow + kt * 32);
      f32x4 acc[2];
      acc[0] = (f32x4){0.f, 0.f, 0.f, 0.f};
      acc[1] = (f32x4){0.f, 0.f, 0.f, 0.f};
      #pragma unroll
      for (int kt = 0; kt < 4; kt++) {
        acc[0] = __builtin_amdgcn_mfma_f32_16x16x32_bf16(afr[0][kt], bfr[kt], acc[0], 0, 0, 0);
        acc[1] = __builtin_amdgcn_mfma_f32_16x16x32_bf16(afr[1][kt], bfr[kt], acc[1], 0, 0, 0);
      }
      float bj = b1[j];
      #pragma unroll
      for (int rt = 0; rt < 2; rt++)
        #pragma unroll
        for (int r = 0; r < 4; r++) {
          int nl = rt * 16 + lg * 4 + r;
          float tv = fmaxf(acc[rt][r] + bj, 0.f);
          tS[nl][(((j >> 3) ^ (nl & 7)) * 8) + (j & 7)] = (short)f2bf(tv);
        }
    }
  }
  __syncthreads();
  // ---- GEMM2: t [32 x 512] @ W2^T -> [32 x 128], +b2, +xn residual ---------
  {
    for (int ci = 0; ci < 2; ci++) {
      int c = (w * 2 + ci) * 16 + ll;
      const unsigned short* wrow = w2b + (size_t)c * 512 + lg * 8;
      short8 bfr[16];
      #pragma unroll
      for (int kt = 0; kt < 16; kt++) bfr[kt] = *(const short8*)(wrow + kt * 32);
      float bj = b2[c];
      #pragma unroll
      for (int rt = 0; rt < 2; rt++) {
        int arow = rt * 16 + ll;
        f32x4 acc = {0.f, 0.f, 0.f, 0.f};
        #pragma unroll
        for (int kt = 0; kt < 16; kt++) {
          short8 a = *(const short8*)&tS[arow][((kt * 4 + lg) ^ (ll & 7)) * 8];
          acc = __builtin_amdgcn_mfma_f32_16x16x32_bf16(a, bfr[kt], acc, 0, 0, 0);
        }
        #pragma unroll
        for (int r = 0; r < 4; r++) {
          int node = node0 + rt * 16 + lg * 4 + r;
          if (node < n)
            out[(size_t)node * HID + c] = xn[(size_t)node * HID + c] + acc[r] + bj;
        }
      }
    }
  }
}

extern "C" void kernel_launch(void* const* d_in, const int* in_sizes, int n_in,
                              void* d_out, int out_size, void* d_ws, size_t ws_size,
                              hipStream_t stream) {
  const float* x     = (const float*)d_in[0];
  const int*   ei    = (const int*)d_in[1];
  const float* attr  = (const float*)d_in[2];
  const float* ln1_g = (const float*)d_in[3];
  const float* ln1_b = (const float*)d_in[4];
  const float* Wq    = (const float*)d_in[5];
  const float* bq    = (const float*)d_in[6];
  const float* Wk    = (const float*)d_in[7];
  const float* bk    = (const float*)d_in[8];
  const float* Wv    = (const float*)d_in[9];
  const float* bv    = (const float*)d_in[10];
  const float* We    = (const float*)d_in[11];
  const float* Wskip = (const float*)d_in[12];
  const float* bskip = (const float*)d_in[13];
  const float* Wbeta = (const float*)d_in[14];
  const float* ln2_g = (const float*)d_in[15];
  const float* ln2_b = (const float*)d_in[16];
  const float* W1    = (const float*)d_in[17];
  const float* b1    = (const float*)d_in[18];
  const float* W2    = (const float*)d_in[19];
  const float* b2    = (const float*)d_in[20];
  float* out = (float*)d_out;
  float* ws  = (float*)d_ws;

  size_t NH = (size_t)N_NODES * HID;  // 6.4M
  float* q  = ws;
  float* s  = ws + NH;
  float* xn = ws + 2 * NH;
  unsigned short* kvb = (unsigned short*)(ws + 3 * NH);  // [N][256] bf16 (k|v)
  int* deg       = (int*)(ws + 4 * NH);
  int* row_start = deg + N_NODES;
  int* cursor    = row_start + N_NODES;
  int* csr_src   = cursor + N_NODES;
  // 3*N + E ints = 950000 (multiple of 4) -> csr_attr stays 16B-aligned
  float4* csr_attr = (float4*)(ws + 4 * NH + 950000);
  unsigned short* wqkvs = (unsigned short*)(ws + 4 * NH + 950000 + (size_t)E_EDGES * 4);
  unsigned short* w1b   = wqkvs + 65536;
  unsigned short* w2b   = w1b + 65536;

  hipMemsetAsync(deg, 0, N_NODES * sizeof(int), stream);

  wcvt_kernel<<<192, 256, 0, stream>>>(
      (const float4*)Wq, (const float4*)Wk, (const float4*)Wv,
      (const float4*)Wskip, (const float4*)W1, (const float4*)W2,
      wqkvs, w1b, w2b);
  qkvs_kernel<<<(N_NODES + 63) / 64, 256, 0, stream>>>(
      x, ln1_g, ln1_b, wqkvs, bq, bk, bv, bskip, q, kvb, s, N_NODES);
  count_kernel<<<(E_EDGES + 255) / 256, 256, 0, stream>>>(ei, deg);
  scan_kernel<<<1, 1024, 0, stream>>>(deg, row_start, cursor, N_NODES);
  scatter_kernel<<<(E_EDGES + 255) / 256, 256, 0, stream>>>(
      ei, (const float4*)attr, cursor, csr_src, csr_attr);
  gather_kernel<<<(N_NODES * 64 + 255) / 256, 256, 0, stream>>>(
      row_start, deg, csr_src, csr_attr, We, q, kvb, x, s, Wbeta, xn, N_NODES);
  mlp_kernel<<<(N_NODES + 31) / 32, 256, 0, stream>>>(
      xn, ln2_g, ln2_b, w1b, b1, w2b, b2, out, N_NODES);
}

// Round 6
// 442.594 us; speedup vs baseline: 2.8352x; 1.0443x over previous
//
#include <hip/hip_runtime.h>

#define N_NODES 50000
#define E_EDGES 800000
#define HID 128

typedef __attribute__((ext_vector_type(8))) short short8;
typedef __attribute__((ext_vector_type(4))) float f32x4;

static __device__ __forceinline__ unsigned short f2bf(float f) {
  unsigned int u = __builtin_bit_cast(unsigned int, f);
  u += 0x7fff + ((u >> 16) & 1);  // round-to-nearest-even
  return (unsigned short)(u >> 16);
}
static __device__ __forceinline__ float bf2f(unsigned short u) {
  return __builtin_bit_cast(float, (unsigned int)u << 16);
}

// ---- weight conversion fp32 -> bf16 (Wq|Wk|Wv|Wskip stacked, W1, W2) --------
__global__ __launch_bounds__(256) void wcvt_kernel(
    const float4* __restrict__ Wq, const float4* __restrict__ Wk,
    const float4* __restrict__ Wv, const float4* __restrict__ Ws,
    const float4* __restrict__ W1, const float4* __restrict__ W2,
    unsigned short* __restrict__ wqkvs, unsigned short* __restrict__ w1b,
    unsigned short* __restrict__ w2b)
{
  int i = blockIdx.x * 256 + threadIdx.x;  // [0, 49152) float4 groups
  const float4* src;
  unsigned short* dst;
  if (i < 16384) {
    int part = i >> 12;
    src = ((part == 0) ? Wq : (part == 1) ? Wk : (part == 2) ? Wv : Ws) + (i & 4095);
    dst = wqkvs + i * 4;
  } else if (i < 32768) {
    src = W1 + (i - 16384); dst = w1b + (size_t)(i - 16384) * 4;
  } else {
    src = W2 + (i - 32768); dst = w2b + (size_t)(i - 32768) * 4;
  }
  float4 v = *src;
  ushort4 o;
  o.x = f2bf(v.x); o.y = f2bf(v.y); o.z = f2bf(v.z); o.w = f2bf(v.w);
  *(ushort4*)dst = o;
}

// ---- fused LN1 + QKVS projection via bf16 MFMA ------------------------------
// block: 256 thr, 64 nodes. wave w owns matrix w (128 cols) x 4 row-tiles.
// k,v written interleaved bf16 kv[node][pair*4]={k0,k1,v0,v1}; q,s fp32.
__global__ __launch_bounds__(256) void qkvs_kernel(
    const float* __restrict__ x,
    const float* __restrict__ g1, const float* __restrict__ bln,
    const unsigned short* __restrict__ wqkvs,
    const float* __restrict__ bq, const float* __restrict__ bk,
    const float* __restrict__ bv, const float* __restrict__ bs,
    float* __restrict__ q, unsigned short* __restrict__ kvb,
    float* __restrict__ s, int n)
{
  __shared__ short lnA[64][128];
  int node0 = blockIdx.x * 64;
  int tid = threadIdx.x;
  int g = tid >> 4, gl = tid & 15, c0 = gl * 8;
  {
    float gv[8], bv2[8];
    *(float4*)&gv[0] = *(const float4*)(g1 + c0);
    *(float4*)&gv[4] = *(const float4*)(g1 + c0 + 4);
    *(float4*)&bv2[0] = *(const float4*)(bln + c0);
    *(float4*)&bv2[4] = *(const float4*)(bln + c0 + 4);
    for (int ni = 0; ni < 4; ni++) {
      int nl = ni * 16 + g;
      int node = node0 + nl;
      short8 h8 = {0, 0, 0, 0, 0, 0, 0, 0};
      if (node < n) {
        float vals[8];
        const float* row = x + (size_t)node * HID + c0;
        *(float4*)&vals[0] = *(const float4*)row;
        *(float4*)&vals[4] = *(const float4*)(row + 4);
        float sum = 0.f;
        #pragma unroll
        for (int j = 0; j < 8; j++) sum += vals[j];
        sum += __shfl_xor(sum, 8); sum += __shfl_xor(sum, 4);
        sum += __shfl_xor(sum, 2); sum += __shfl_xor(sum, 1);
        float mu = sum * (1.f / 128.f);
        float sq = 0.f;
        #pragma unroll
        for (int j = 0; j < 8; j++) { float d = vals[j] - mu; sq += d * d; }
        sq += __shfl_xor(sq, 8); sq += __shfl_xor(sq, 4);
        sq += __shfl_xor(sq, 2); sq += __shfl_xor(sq, 1);
        float rstd = rsqrtf(sq * (1.f / 128.f) + 1e-5f);
        #pragma unroll
        for (int j = 0; j < 8; j++)
          h8[j] = (short)f2bf((vals[j] - mu) * rstd * gv[j] + bv2[j]);
      }
      *(short8*)&lnA[nl][(gl ^ (nl & 7)) * 8] = h8;
    }
  }
  __syncthreads();
  int w = tid >> 6, lane = tid & 63;
  int lg = lane >> 4, ll = lane & 15;
  short8 afr[4][4];
  #pragma unroll
  for (int rt = 0; rt < 4; rt++) {
    int arow = rt * 16 + ll;
    #pragma unroll
    for (int kt = 0; kt < 4; kt++)
      afr[rt][kt] = *(const short8*)&lnA[arow][((kt * 4 + lg) ^ (ll & 7)) * 8];
  }
  const float* biasp = (w == 0) ? bq : (w == 1) ? bk : (w == 2) ? bv : bs;
  for (int ci = 0; ci < 8; ci++) {
    int j = (w * 8 + ci) * 16 + ll;  // global col in [w*128, w*128+128)
    int jj = j & 127;
    const unsigned short* wrow = wqkvs + (size_t)j * 128 + lg * 8;
    short8 bfr[4];
    #pragma unroll
    for (int kt = 0; kt < 4; kt++) bfr[kt] = *(const short8*)(wrow + kt * 32);
    f32x4 acc[4];
    #pragma unroll
    for (int rt = 0; rt < 4; rt++) acc[rt] = (f32x4){0.f, 0.f, 0.f, 0.f};
    #pragma unroll
    for (int kt = 0; kt < 4; kt++)
      #pragma unroll
      for (int rt = 0; rt < 4; rt++)
        acc[rt] = __builtin_amdgcn_mfma_f32_16x16x32_bf16(afr[rt][kt], bfr[kt], acc[rt], 0, 0, 0);
    float bj = biasp[jj];
    #pragma unroll
    for (int rt = 0; rt < 4; rt++)
      #pragma unroll
      for (int r = 0; r < 4; r++) {
        int node = node0 + rt * 16 + lg * 4 + r;
        if (node < n) {
          float val = acc[rt][r] + bj;
          if (w == 0) q[(size_t)node * HID + jj] = val;
          else if (w == 1) kvb[(size_t)node * 256 + (jj >> 1) * 4 + (jj & 1)] = f2bf(val);
          else if (w == 2) kvb[(size_t)node * 256 + (jj >> 1) * 4 + 2 + (jj & 1)] = f2bf(val);
          else s[(size_t)node * HID + jj] = val;
        }
      }
  }
}

// -------- CSR build: count degrees ------------------------------------------
__global__ __launch_bounds__(256) void count_kernel(
    const int* __restrict__ ei, int* __restrict__ deg)
{
  int e = blockIdx.x * 256 + threadIdx.x;
  if (e < E_EDGES) atomicAdd(deg + ei[E_EDGES + e], 1);
}

// -------- CSR build: exclusive scan (single block, 1024 threads) -------------
__global__ __launch_bounds__(1024) void scan_kernel(
    const int* __restrict__ deg, int* __restrict__ row_start,
    int* __restrict__ cursor, int n)
{
  __shared__ int sums[1024];
  int tid = threadIdx.x;
  int chunk = (n + 1023) / 1024;
  int start = tid * chunk;
  int end = min(start + chunk, n);
  int s = 0;
  for (int i = start; i < end; i++) s += deg[i];
  sums[tid] = s;
  __syncthreads();
  for (int off = 1; off < 1024; off <<= 1) {
    int t = (tid >= off) ? sums[tid - off] : 0;
    __syncthreads();
    sums[tid] += t;
    __syncthreads();
  }
  int run = sums[tid] - s;
  for (int i = start; i < end; i++) {
    row_start[i] = run;
    cursor[i] = run;
    run += deg[i];
  }
}

// -------- CSR build: scatter packed (src, attr) records ----------------------
__global__ __launch_bounds__(256) void scatter_kernel(
    const int* __restrict__ ei, const float4* __restrict__ attr,
    int* __restrict__ cursor,
    int* __restrict__ csr_src, float4* __restrict__ csr_attr)
{
  int e = blockIdx.x * 256 + threadIdx.x;
  if (e >= E_EDGES) return;
  int dst = ei[E_EDGES + e];
  int pos = atomicAdd(cursor + dst, 1);
  csr_src[pos] = ei[e];
  csr_attr[pos] = attr[e];
}

// -------- Gather + combine: 1 wave per dst node, lane = 2 channels -----------
// Uses q·(k+e) = q·k + (q^T We)·attr  and  Σ a_j e_j = We (Σ a_j attr_j).
// kv interleaved: one ushort4 {k0,k1,v0,v1} per lane per edge (512B/edge/wave).
__global__ __launch_bounds__(256) void gather_kernel(
    const int* __restrict__ row_start, const int* __restrict__ deg,
    const int* __restrict__ csr_src, const float4* __restrict__ csr_attr,
    const float* __restrict__ We,
    const float* __restrict__ q, const unsigned short* __restrict__ kvb,
    const float* __restrict__ x, const float* __restrict__ sk,
    const float* __restrict__ Wb, float* __restrict__ xn, int n)
{
  int node = (blockIdx.x * blockDim.x + threadIdx.x) >> 6;
  if (node >= n) return;
  int lane = threadIdx.x & 63;
  int c0 = lane * 2;
  float4 w0 = *(const float4*)(We + c0 * 4);      // We row for channel c0
  float4 w1 = *(const float4*)(We + c0 * 4 + 4);  // We row for channel c0+1
  float2 qd = *(const float2*)(q + (size_t)node * HID + c0);
  // qwe[t] = sum over this head's 32 channels of q[c]*We[c][t]
  float qwe0 = qd.x * w0.x + qd.y * w1.x;
  float qwe1 = qd.x * w0.y + qd.y * w1.y;
  float qwe2 = qd.x * w0.z + qd.y * w1.z;
  float qwe3 = qd.x * w0.w + qd.y * w1.w;
  qwe0 += __shfl_xor(qwe0, 1); qwe0 += __shfl_xor(qwe0, 2);
  qwe0 += __shfl_xor(qwe0, 4); qwe0 += __shfl_xor(qwe0, 8);
  qwe1 += __shfl_xor(qwe1, 1); qwe1 += __shfl_xor(qwe1, 2);
  qwe1 += __shfl_xor(qwe1, 4); qwe1 += __shfl_xor(qwe1, 8);
  qwe2 += __shfl_xor(qwe2, 1); qwe2 += __shfl_xor(qwe2, 2);
  qwe2 += __shfl_xor(qwe2, 4); qwe2 += __shfl_xor(qwe2, 8);
  qwe3 += __shfl_xor(qwe3, 1); qwe3 += __shfl_xor(qwe3, 2);
  qwe3 += __shfl_xor(qwe3, 4); qwe3 += __shfl_xor(qwe3, 8);
  float acc0 = 0.f, acc1 = 0.f, den = 0.f;
  float aat0 = 0.f, aat1 = 0.f, aat2 = 0.f, aat3 = 0.f;
  int rs = row_start[node];
  int re = rs + deg[node];
  const float s2 = 0.17677669529663687f * 1.4426950408889634f;  // /sqrt(32)*log2e
  #pragma unroll 2
  for (int j = rs; j < re; j++) {
    int src = csr_src[j];
    float4 a4 = csr_attr[j];
    ushort4 kv4 = *(const ushort4*)(kvb + (size_t)src * 256 + lane * 4);
    float dot = qd.x * bf2f(kv4.x) + qd.y * bf2f(kv4.y);
    dot += __shfl_xor(dot, 1);
    dot += __shfl_xor(dot, 2);
    dot += __shfl_xor(dot, 4);
    dot += __shfl_xor(dot, 8);
    float a = exp2f((dot + qwe0 * a4.x + qwe1 * a4.y +
                     qwe2 * a4.z + qwe3 * a4.w) * s2);  // max-free softmax
    den += a;
    aat0 += a * a4.x; aat1 += a * a4.y;
    aat2 += a * a4.z; aat3 += a * a4.w;
    acc0 += a * bf2f(kv4.z);
    acc1 += a * bf2f(kv4.w);
  }
  float inv = 1.0f / (den + 1e-16f);
  float o0 = (acc0 + w0.x * aat0 + w0.y * aat1 + w0.z * aat2 + w0.w * aat3) * inv;
  float o1 = (acc1 + w1.x * aat0 + w1.y * aat1 + w1.z * aat2 + w1.w * aat3) * inv;
  // ---- fused combine: beta gate + first residual ----
  float2 skp = *(const float2*)(sk + (size_t)node * HID + c0);
  float bpart = o0 * (Wb[c0] + Wb[256 + c0]) + o1 * (Wb[c0 + 1] + Wb[256 + c0 + 1]) +
                skp.x * (Wb[128 + c0] - Wb[256 + c0]) +
                skp.y * (Wb[128 + c0 + 1] - Wb[256 + c0 + 1]);
  for (int m = 32; m >= 1; m >>= 1) bpart += __shfl_xor(bpart, m);
  float beta = 1.0f / (1.0f + exp2f(-bpart * 1.4426950408889634f));
  float h0 = beta * skp.x + (1.0f - beta) * o0;
  float h1 = beta * skp.y + (1.0f - beta) * o1;
  float2 xv = *(const float2*)(x + (size_t)node * HID + c0);
  *(float2*)(xn + (size_t)node * HID + c0) = make_float2(xv.x + h0, xv.y + h1);
}

// ---- fused LN2 + MLP (GEMM1 relu GEMM2) via bf16 MFMA + residual ------------
// block: 256 thr, 32 nodes. wave w owns a col-quarter across both row-tiles.
__global__ __launch_bounds__(256) void mlp_kernel(
    const float* __restrict__ xn,
    const float* __restrict__ g2, const float* __restrict__ b2ln,
    const unsigned short* __restrict__ w1b, const float* __restrict__ b1,
    const unsigned short* __restrict__ w2b, const float* __restrict__ b2,
    float* __restrict__ out, int n)
{
  __shared__ short lnA[32][128];
  __shared__ short tS[32][512];
  int node0 = blockIdx.x * 32;
  int tid = threadIdx.x;
  int g = tid >> 4, gl = tid & 15, c0 = gl * 8;
  {
    float gv[8], bv2[8];
    *(float4*)&gv[0] = *(const float4*)(g2 + c0);
    *(float4*)&gv[4] = *(const float4*)(g2 + c0 + 4);
    *(float4*)&bv2[0] = *(const float4*)(b2ln + c0);
    *(float4*)&bv2[4] = *(const float4*)(b2ln + c0 + 4);
    for (int ni = 0; ni < 2; ni++) {
      int nl = ni * 16 + g;
      int node = node0 + nl;
      short8 h8 = {0, 0, 0, 0, 0, 0, 0, 0};
      if (node < n) {
        float vals[8];
        const float* row = xn + (size_t)node * HID + c0;
        *(float4*)&vals[0] = *(const float4*)row;
        *(float4*)&vals[4] = *(const float4*)(row + 4);
        float sum = 0.f;
        #pragma unroll
        for (int j = 0; j < 8; j++) sum += vals[j];
        sum += __shfl_xor(sum, 8); sum += __shfl_xor(sum, 4);
        sum += __shfl_xor(sum, 2); sum += __shfl_xor(sum, 1);
        float mu = sum * (1.f / 128.f);
        float sq = 0.f;
        #pragma unroll
        for (int j = 0; j < 8; j++) { float d = vals[j] - mu; sq += d * d; }
        sq += __shfl_xor(sq, 8); sq += __shfl_xor(sq, 4);
        sq += __shfl_xor(sq, 2); sq += __shfl_xor(sq, 1);
        float rstd = rsqrtf(sq * (1.f / 128.f) + 1e-5f);
        #pragma unroll
        for (int j = 0; j < 8; j++)
          h8[j] = (short)f2bf((vals[j] - mu) * rstd * gv[j] + bv2[j]);
      }
      *(short8*)&lnA[nl][(gl ^ (nl & 7)) * 8] = h8;
    }
  }
  __syncthreads();
  int w = tid >> 6, lane = tid & 63;
  int lg = lane >> 4, ll = lane & 15;
  // ---- GEMM1: [32 x 128] @ W1^T -> t [32 x 512], +b1, relu, bf16 to LDS ----
  {
    short8 afr[2][4];
    #pragma unroll
    for (int rt = 0; rt < 2; rt++) {
      int arow = rt * 16 + ll;
      #pragma unroll
      for (int kt = 0; kt < 4; kt++)
        afr[rt][kt] = *(const short8*)&lnA[arow][((kt * 4 + lg) ^ (ll & 7)) * 8];
    }
    for (int ci = 0; ci < 8; ci++) {
      int j = (w * 8 + ci) * 16 + ll;
      const unsigned short* wrow = w1b + (size_t)j * 128 + lg * 8;
      short8 bfr[4];
      #pragma unroll
      for (int kt = 0; kt < 4; kt++) bfr[kt] = *(const short8*)(wrow + kt * 32);
      f32x4 acc[2];
      acc[0] = (f32x4){0.f, 0.f, 0.f, 0.f};
      acc[1] = (f32x4){0.f, 0.f, 0.f, 0.f};
      #pragma unroll
      for (int kt = 0; kt < 4; kt++) {
        acc[0] = __builtin_amdgcn_mfma_f32_16x16x32_bf16(afr[0][kt], bfr[kt], acc[0], 0, 0, 0);
        acc[1] = __builtin_amdgcn_mfma_f32_16x16x32_bf16(afr[1][kt], bfr[kt], acc[1], 0, 0, 0);
      }
      float bj = b1[j];
      #pragma unroll
      for (int rt = 0; rt < 2; rt++)
        #pragma unroll
        for (int r = 0; r < 4; r++) {
          int nl = rt * 16 + lg * 4 + r;
          float tv = fmaxf(acc[rt][r] + bj, 0.f);
          tS[nl][(((j >> 3) ^ (nl & 7)) * 8) + (j & 7)] = (short)f2bf(tv);
        }
    }
  }
  __syncthreads();
  // ---- GEMM2: t [32 x 512] @ W2^T -> [32 x 128], +b2, +xn residual ---------
  {
    for (int ci = 0; ci < 2; ci++) {
      int c = (w * 2 + ci) * 16 + ll;
      const unsigned short* wrow = w2b + (size_t)c * 512 + lg * 8;
      short8 bfr[16];
      #pragma unroll
      for (int kt = 0; kt < 16; kt++) bfr[kt] = *(const short8*)(wrow + kt * 32);
      float bj = b2[c];
      #pragma unroll
      for (int rt = 0; rt < 2; rt++) {
        int arow = rt * 16 + ll;
        f32x4 acc = {0.f, 0.f, 0.f, 0.f};
        #pragma unroll
        for (int kt = 0; kt < 16; kt++) {
          short8 a = *(const short8*)&tS[arow][((kt * 4 + lg) ^ (ll & 7)) * 8];
          acc = __builtin_amdgcn_mfma_f32_16x16x32_bf16(a, bfr[kt], acc, 0, 0, 0);
        }
        #pragma unroll
        for (int r = 0; r < 4; r++) {
          int node = node0 + rt * 16 + lg * 4 + r;
          if (node < n)
            out[(size_t)node * HID + c] = xn[(size_t)node * HID + c] + acc[r] + bj;
        }
      }
    }
  }
}

extern "C" void kernel_launch(void* const* d_in, const int* in_sizes, int n_in,
                              void* d_out, int out_size, void* d_ws, size_t ws_size,
                              hipStream_t stream) {
  const float* x     = (const float*)d_in[0];
  const int*   ei    = (const int*)d_in[1];
  const float* attr  = (const float*)d_in[2];
  const float* ln1_g = (const float*)d_in[3];
  const float* ln1_b = (const float*)d_in[4];
  const float* Wq    = (const float*)d_in[5];
  const float* bq    = (const float*)d_in[6];
  const float* Wk    = (const float*)d_in[7];
  const float* bk    = (const float*)d_in[8];
  const float* Wv    = (const float*)d_in[9];
  const float* bv    = (const float*)d_in[10];
  const float* We    = (const float*)d_in[11];
  const float* Wskip = (const float*)d_in[12];
  const float* bskip = (const float*)d_in[13];
  const float* Wbeta = (const float*)d_in[14];
  const float* ln2_g = (const float*)d_in[15];
  const float* ln2_b = (const float*)d_in[16];
  const float* W1    = (const float*)d_in[17];
  const float* b1    = (const float*)d_in[18];
  const float* W2    = (const float*)d_in[19];
  const float* b2    = (const float*)d_in[20];
  float* out = (float*)d_out;
  float* ws  = (float*)d_ws;

  size_t NH = (size_t)N_NODES * HID;  // 6.4M
  float* q  = ws;
  float* s  = ws + NH;
  float* xn = ws + 2 * NH;
  unsigned short* kvb = (unsigned short*)(ws + 3 * NH);  // [N][256] bf16 interleaved
  int* deg       = (int*)(ws + 4 * NH);
  int* row_start = deg + N_NODES;
  int* cursor    = row_start + N_NODES;
  int* csr_src   = cursor + N_NODES;
  // 3*N + E ints = 950000 (multiple of 4) -> csr_attr stays 16B-aligned
  float4* csr_attr = (float4*)(ws + 4 * NH + 950000);
  unsigned short* wqkvs = (unsigned short*)(ws + 4 * NH + 950000 + (size_t)E_EDGES * 4);
  unsigned short* w1b   = wqkvs + 65536;
  unsigned short* w2b   = w1b + 65536;

  hipMemsetAsync(deg, 0, N_NODES * sizeof(int), stream);

  wcvt_kernel<<<192, 256, 0, stream>>>(
      (const float4*)Wq, (const float4*)Wk, (const float4*)Wv,
      (const float4*)Wskip, (const float4*)W1, (const float4*)W2,
      wqkvs, w1b, w2b);
  qkvs_kernel<<<(N_NODES + 63) / 64, 256, 0, stream>>>(
      x, ln1_g, ln1_b, wqkvs, bq, bk, bv, bskip, q, kvb, s, N_NODES);
  count_kernel<<<(E_EDGES + 255) / 256, 256, 0, stream>>>(ei, deg);
  scan_kernel<<<1, 1024, 0, stream>>>(deg, row_start, cursor, N_NODES);
  scatter_kernel<<<(E_EDGES + 255) / 256, 256, 0, stream>>>(
      ei, (const float4*)attr, cursor, csr_src, csr_attr);
  gather_kernel<<<(N_NODES * 64 + 255) / 256, 256, 0, stream>>>(
      row_start, deg, csr_src, csr_attr, We, q, kvb, x, s, Wbeta, xn, N_NODES);
  mlp_kernel<<<(N_NODES + 31) / 32, 256, 0, stream>>>(
      xn, ln2_g, ln2_b, w1b, b1, w2b, b2, out, N_NODES);
}

// Round 7
// 434.336 us; speedup vs baseline: 2.8891x; 1.0190x over previous
//
#include <hip/hip_runtime.h>

#define N_NODES 50000
#define E_EDGES 800000
#define HID 128
#define NQB 782  // ceil(50000/64) node-tile blocks in the fused qkvs kernel

typedef __attribute__((ext_vector_type(8))) short short8;
typedef __attribute__((ext_vector_type(4))) float f32x4;

static __device__ __forceinline__ unsigned short f2bf(float f) {
  unsigned int u = __builtin_bit_cast(unsigned int, f);
  u += 0x7fff + ((u >> 16) & 1);  // round-to-nearest-even
  return (unsigned short)(u >> 16);
}
static __device__ __forceinline__ float bf2f(unsigned short u) {
  return __builtin_bit_cast(float, (unsigned int)u << 16);
}
static __device__ __forceinline__ unsigned char f2fp8(float f) {
  return (unsigned char)(__builtin_amdgcn_cvt_pk_fp8_f32(f, f, 0, false) & 0xff);
}

// ---- weight conversion fp32 -> bf16 (Wq|Wk|Wv|Wskip stacked, W1, W2) --------
__global__ __launch_bounds__(256) void wcvt_kernel(
    const float4* __restrict__ Wq, const float4* __restrict__ Wk,
    const float4* __restrict__ Wv, const float4* __restrict__ Ws,
    const float4* __restrict__ W1, const float4* __restrict__ W2,
    unsigned short* __restrict__ wqkvs, unsigned short* __restrict__ w1b,
    unsigned short* __restrict__ w2b)
{
  int i = blockIdx.x * 256 + threadIdx.x;  // [0, 49152) float4 groups
  const float4* src;
  unsigned short* dst;
  if (i < 16384) {
    int part = i >> 12;
    src = ((part == 0) ? Wq : (part == 1) ? Wk : (part == 2) ? Wv : Ws) + (i & 4095);
    dst = wqkvs + i * 4;
  } else if (i < 32768) {
    src = W1 + (i - 16384); dst = w1b + (size_t)(i - 16384) * 4;
  } else {
    src = W2 + (i - 32768); dst = w2b + (size_t)(i - 32768) * 4;
  }
  float4 v = *src;
  ushort4 o;
  o.x = f2bf(v.x); o.y = f2bf(v.y); o.z = f2bf(v.z); o.w = f2bf(v.w);
  *(ushort4*)dst = o;
}

// ---- fused [LN1 + QKVS projection via bf16 MFMA | degree count] -------------
// blocks [0,NQB): 64-node tile; wave w owns matrix w (128 cols) x 4 row-tiles.
// q bf16, skip bf16, k/v fp8 interleaved kv[node][pair*4]={k0,k1,v0,v1} bytes.
// blocks [NQB, 2*NQB): grid-stride degree count (independent work, overlapped).
__global__ __launch_bounds__(256) void qkvs_kernel(
    const float* __restrict__ x,
    const float* __restrict__ g1, const float* __restrict__ bln,
    const unsigned short* __restrict__ wqkvs,
    const float* __restrict__ bq, const float* __restrict__ bk,
    const float* __restrict__ bv, const float* __restrict__ bs,
    unsigned short* __restrict__ qb, unsigned char* __restrict__ kvb,
    unsigned short* __restrict__ sb,
    const int* __restrict__ ei, int* __restrict__ deg, int n)
{
  if (blockIdx.x >= NQB) {  // ---- degree count path ----
    for (int e = (blockIdx.x - NQB) * 256 + threadIdx.x; e < E_EDGES;
         e += NQB * 256)
      atomicAdd(deg + ei[E_EDGES + e], 1);
    return;
  }
  __shared__ short lnA[64][128];
  int node0 = blockIdx.x * 64;
  int tid = threadIdx.x;
  int g = tid >> 4, gl = tid & 15, c0 = gl * 8;
  {
    float gv[8], bv2[8];
    *(float4*)&gv[0] = *(const float4*)(g1 + c0);
    *(float4*)&gv[4] = *(const float4*)(g1 + c0 + 4);
    *(float4*)&bv2[0] = *(const float4*)(bln + c0);
    *(float4*)&bv2[4] = *(const float4*)(bln + c0 + 4);
    for (int ni = 0; ni < 4; ni++) {
      int nl = ni * 16 + g;
      int node = node0 + nl;
      short8 h8 = {0, 0, 0, 0, 0, 0, 0, 0};
      if (node < n) {
        float vals[8];
        const float* row = x + (size_t)node * HID + c0;
        *(float4*)&vals[0] = *(const float4*)row;
        *(float4*)&vals[4] = *(const float4*)(row + 4);
        float sum = 0.f;
        #pragma unroll
        for (int j = 0; j < 8; j++) sum += vals[j];
        sum += __shfl_xor(sum, 8); sum += __shfl_xor(sum, 4);
        sum += __shfl_xor(sum, 2); sum += __shfl_xor(sum, 1);
        float mu = sum * (1.f / 128.f);
        float sq = 0.f;
        #pragma unroll
        for (int j = 0; j < 8; j++) { float d = vals[j] - mu; sq += d * d; }
        sq += __shfl_xor(sq, 8); sq += __shfl_xor(sq, 4);
        sq += __shfl_xor(sq, 2); sq += __shfl_xor(sq, 1);
        float rstd = rsqrtf(sq * (1.f / 128.f) + 1e-5f);
        #pragma unroll
        for (int j = 0; j < 8; j++)
          h8[j] = (short)f2bf((vals[j] - mu) * rstd * gv[j] + bv2[j]);
      }
      *(short8*)&lnA[nl][(gl ^ (nl & 7)) * 8] = h8;
    }
  }
  __syncthreads();
  int w = tid >> 6, lane = tid & 63;
  int lg = lane >> 4, ll = lane & 15;
  short8 afr[4][4];
  #pragma unroll
  for (int rt = 0; rt < 4; rt++) {
    int arow = rt * 16 + ll;
    #pragma unroll
    for (int kt = 0; kt < 4; kt++)
      afr[rt][kt] = *(const short8*)&lnA[arow][((kt * 4 + lg) ^ (ll & 7)) * 8];
  }
  const float* biasp = (w == 0) ? bq : (w == 1) ? bk : (w == 2) ? bv : bs;
  for (int ci = 0; ci < 8; ci++) {
    int j = (w * 8 + ci) * 16 + ll;  // global col in [w*128, w*128+128)
    int jj = j & 127;
    const unsigned short* wrow = wqkvs + (size_t)j * 128 + lg * 8;
    short8 bfr[4];
    #pragma unroll
    for (int kt = 0; kt < 4; kt++) bfr[kt] = *(const short8*)(wrow + kt * 32);
    f32x4 acc[4];
    #pragma unroll
    for (int rt = 0; rt < 4; rt++) acc[rt] = (f32x4){0.f, 0.f, 0.f, 0.f};
    #pragma unroll
    for (int kt = 0; kt < 4; kt++)
      #pragma unroll
      for (int rt = 0; rt < 4; rt++)
        acc[rt] = __builtin_amdgcn_mfma_f32_16x16x32_bf16(afr[rt][kt], bfr[kt], acc[rt], 0, 0, 0);
    float bj = biasp[jj];
    #pragma unroll
    for (int rt = 0; rt < 4; rt++)
      #pragma unroll
      for (int r = 0; r < 4; r++) {
        int node = node0 + rt * 16 + lg * 4 + r;
        if (node < n) {
          float val = acc[rt][r] + bj;
          if (w == 0) qb[(size_t)node * HID + jj] = f2bf(val);
          else if (w == 1) kvb[(size_t)node * 256 + (jj >> 1) * 4 + (jj & 1)] = f2fp8(val);
          else if (w == 2) kvb[(size_t)node * 256 + (jj >> 1) * 4 + 2 + (jj & 1)] = f2fp8(val);
          else sb[(size_t)node * HID + jj] = f2bf(val);
        }
      }
  }
}

// -------- CSR build: exclusive scan (single block, 1024 threads) -------------
__global__ __launch_bounds__(1024) void scan_kernel(
    const int* __restrict__ deg, int* __restrict__ row_start,
    int* __restrict__ cursor, int n)
{
  __shared__ int sums[1024];
  int tid = threadIdx.x;
  int chunk = (n + 1023) / 1024;
  int start = tid * chunk;
  int end = min(start + chunk, n);
  int s = 0;
  for (int i = start; i < end; i++) s += deg[i];
  sums[tid] = s;
  __syncthreads();
  for (int off = 1; off < 1024; off <<= 1) {
    int t = (tid >= off) ? sums[tid - off] : 0;
    __syncthreads();
    sums[tid] += t;
    __syncthreads();
  }
  int run = sums[tid] - s;
  for (int i = start; i < end; i++) {
    row_start[i] = run;
    cursor[i] = run;
    run += deg[i];
  }
}

// -------- CSR build: scatter packed (src, attr) records ----------------------
__global__ __launch_bounds__(256) void scatter_kernel(
    const int* __restrict__ ei, const float4* __restrict__ attr,
    int* __restrict__ cursor,
    int* __restrict__ csr_src, float4* __restrict__ csr_attr)
{
  int e = blockIdx.x * 256 + threadIdx.x;
  if (e >= E_EDGES) return;
  int dst = ei[E_EDGES + e];
  int pos = atomicAdd(cursor + dst, 1);
  csr_src[pos] = ei[e];
  csr_attr[pos] = attr[e];
}

// -------- Gather + combine: 1 wave per dst node, lane = 2 channels -----------
// q·(k+e) = q·k + (q^T We)·attr ;  Σ a_j e_j = We (Σ a_j attr_j).
// kv fp8 interleaved: one uint {k0,k1,v0,v1} per lane per edge (256B/edge/wave).
// Manual 1-deep pipeline: prefetch csr_src[j+1] then issue kv[j+1] after the
// shfl chain so the dependent load pair overlaps the current edge's compute.
__global__ __launch_bounds__(256) void gather_kernel(
    const int* __restrict__ row_start, const int* __restrict__ deg,
    const int* __restrict__ csr_src, const float4* __restrict__ csr_attr,
    const float* __restrict__ We,
    const unsigned short* __restrict__ qb, const unsigned char* __restrict__ kvb,
    const float* __restrict__ x, const unsigned short* __restrict__ sb,
    const float* __restrict__ Wb, unsigned short* __restrict__ xnb, int n)
{
  int node = (blockIdx.x * blockDim.x + threadIdx.x) >> 6;
  if (node >= n) return;
  int lane = threadIdx.x & 63;
  int c0 = lane * 2;
  float4 w0 = *(const float4*)(We + c0 * 4);      // We row for channel c0
  float4 w1 = *(const float4*)(We + c0 * 4 + 4);  // We row for channel c0+1
  ushort2 q2 = *(const ushort2*)(qb + (size_t)node * HID + c0);
  float qx = bf2f(q2.x), qy = bf2f(q2.y);
  float qwe0 = qx * w0.x + qy * w1.x;
  float qwe1 = qx * w0.y + qy * w1.y;
  float qwe2 = qx * w0.z + qy * w1.z;
  float qwe3 = qx * w0.w + qy * w1.w;
  qwe0 += __shfl_xor(qwe0, 1); qwe0 += __shfl_xor(qwe0, 2);
  qwe0 += __shfl_xor(qwe0, 4); qwe0 += __shfl_xor(qwe0, 8);
  qwe1 += __shfl_xor(qwe1, 1); qwe1 += __shfl_xor(qwe1, 2);
  qwe1 += __shfl_xor(qwe1, 4); qwe1 += __shfl_xor(qwe1, 8);
  qwe2 += __shfl_xor(qwe2, 1); qwe2 += __shfl_xor(qwe2, 2);
  qwe2 += __shfl_xor(qwe2, 4); qwe2 += __shfl_xor(qwe2, 8);
  qwe3 += __shfl_xor(qwe3, 1); qwe3 += __shfl_xor(qwe3, 2);
  qwe3 += __shfl_xor(qwe3, 4); qwe3 += __shfl_xor(qwe3, 8);
  float acc0 = 0.f, acc1 = 0.f, den = 0.f;
  float aat0 = 0.f, aat1 = 0.f, aat2 = 0.f, aat3 = 0.f;
  int rs = row_start[node];
  int cnt = deg[node];
  int re = rs + cnt;
  const float s2 = 0.17677669529663687f * 1.4426950408889634f;  // /sqrt(32)*log2e
  unsigned kv_cur = 0u;
  if (cnt > 0) {
    int s0 = csr_src[rs];
    kv_cur = *(const unsigned*)(kvb + (size_t)s0 * 256 + lane * 4);
  }
  for (int j = rs; j < re; j++) {
    int s_nxt = (j + 1 < re) ? csr_src[j + 1] : 0;
    float4 a4 = csr_attr[j];
    float k0 = __builtin_amdgcn_cvt_f32_fp8((int)kv_cur, 0);
    float k1 = __builtin_amdgcn_cvt_f32_fp8((int)kv_cur, 1);
    float dot = qx * k0 + qy * k1;
    dot += __shfl_xor(dot, 1);
    dot += __shfl_xor(dot, 2);
    dot += __shfl_xor(dot, 4);
    dot += __shfl_xor(dot, 8);
    unsigned kv_nxt = 0u;
    if (j + 1 < re)
      kv_nxt = *(const unsigned*)(kvb + (size_t)s_nxt * 256 + lane * 4);
    float v0 = __builtin_amdgcn_cvt_f32_fp8((int)kv_cur, 2);
    float v1 = __builtin_amdgcn_cvt_f32_fp8((int)kv_cur, 3);
    float a = exp2f((dot + qwe0 * a4.x + qwe1 * a4.y +
                     qwe2 * a4.z + qwe3 * a4.w) * s2);  // max-free softmax
    den += a;
    aat0 += a * a4.x; aat1 += a * a4.y;
    aat2 += a * a4.z; aat3 += a * a4.w;
    acc0 += a * v0;
    acc1 += a * v1;
    kv_cur = kv_nxt;
  }
  float inv = 1.0f / (den + 1e-16f);
  float o0 = (acc0 + w0.x * aat0 + w0.y * aat1 + w0.z * aat2 + w0.w * aat3) * inv;
  float o1 = (acc1 + w1.x * aat0 + w1.y * aat1 + w1.z * aat2 + w1.w * aat3) * inv;
  // ---- fused combine: beta gate + first residual ----
  ushort2 sp2 = *(const ushort2*)(sb + (size_t)node * HID + c0);
  float skx = bf2f(sp2.x), sky = bf2f(sp2.y);
  float bpart = o0 * (Wb[c0] + Wb[256 + c0]) + o1 * (Wb[c0 + 1] + Wb[256 + c0 + 1]) +
                skx * (Wb[128 + c0] - Wb[256 + c0]) +
                sky * (Wb[128 + c0 + 1] - Wb[256 + c0 + 1]);
  for (int m = 32; m >= 1; m >>= 1) bpart += __shfl_xor(bpart, m);
  float beta = 1.0f / (1.0f + exp2f(-bpart * 1.4426950408889634f));
  float2 xv = *(const float2*)(x + (size_t)node * HID + c0);
  float r0 = xv.x + beta * skx + (1.0f - beta) * o0;
  float r1 = xv.y + beta * sky + (1.0f - beta) * o1;
  ushort2 o2;
  o2.x = f2bf(r0); o2.y = f2bf(r1);
  *(ushort2*)(xnb + (size_t)node * HID + c0) = o2;
}

// ---- fused LN2 + MLP (GEMM1 relu GEMM2) via bf16 MFMA + residual ------------
// block: 256 thr, 32 nodes. wave w owns a col-quarter across both row-tiles.
__global__ __launch_bounds__(256) void mlp_kernel(
    const unsigned short* __restrict__ xnb,
    const float* __restrict__ g2, const float* __restrict__ b2ln,
    const unsigned short* __restrict__ w1b, const float* __restrict__ b1,
    const unsigned short* __restrict__ w2b, const float* __restrict__ b2,
    float* __restrict__ out, int n)
{
  __shared__ short lnA[32][128];
  __shared__ short tS[32][512];
  int node0 = blockIdx.x * 32;
  int tid = threadIdx.x;
  int g = tid >> 4, gl = tid & 15, c0 = gl * 8;
  {
    float gv[8], bv2[8];
    *(float4*)&gv[0] = *(const float4*)(g2 + c0);
    *(float4*)&gv[4] = *(const float4*)(g2 + c0 + 4);
    *(float4*)&bv2[0] = *(const float4*)(b2ln + c0);
    *(float4*)&bv2[4] = *(const float4*)(b2ln + c0 + 4);
    for (int ni = 0; ni < 2; ni++) {
      int nl = ni * 16 + g;
      int node = node0 + nl;
      short8 h8 = {0, 0, 0, 0, 0, 0, 0, 0};
      if (node < n) {
        short8 raw = *(const short8*)(xnb + (size_t)node * HID + c0);
        float vals[8];
        #pragma unroll
        for (int j = 0; j < 8; j++) vals[j] = bf2f((unsigned short)raw[j]);
        float sum = 0.f;
        #pragma unroll
        for (int j = 0; j < 8; j++) sum += vals[j];
        sum += __shfl_xor(sum, 8); sum += __shfl_xor(sum, 4);
        sum += __shfl_xor(sum, 2); sum += __shfl_xor(sum, 1);
        float mu = sum * (1.f / 128.f);
        float sq = 0.f;
        #pragma unroll
        for (int j = 0; j < 8; j++) { float d = vals[j] - mu; sq += d * d; }
        sq += __shfl_xor(sq, 8); sq += __shfl_xor(sq, 4);
        sq += __shfl_xor(sq, 2); sq += __shfl_xor(sq, 1);
        float rstd = rsqrtf(sq * (1.f / 128.f) + 1e-5f);
        #pragma unroll
        for (int j = 0; j < 8; j++)
          h8[j] = (short)f2bf((vals[j] - mu) * rstd * gv[j] + bv2[j]);
      }
      *(short8*)&lnA[nl][(gl ^ (nl & 7)) * 8] = h8;
    }
  }
  __syncthreads();
  int w = tid >> 6, lane = tid & 63;
  int lg = lane >> 4, ll = lane & 15;
  // ---- GEMM1: [32 x 128] @ W1^T -> t [32 x 512], +b1, relu, bf16 to LDS ----
  {
    short8 afr[2][4];
    #pragma unroll
    for (int rt = 0; rt < 2; rt++) {
      int arow = rt * 16 + ll;
      #pragma unroll
      for (int kt = 0; kt < 4; kt++)
        afr[rt][kt] = *(const short8*)&lnA[arow][((kt * 4 + lg) ^ (ll & 7)) * 8];
    }
    for (int ci = 0; ci < 8; ci++) {
      int j = (w * 8 + ci) * 16 + ll;
      const unsigned short* wrow = w1b + (size_t)j * 128 + lg * 8;
      short8 bfr[4];
      #pragma unroll
      for (int kt = 0; kt < 4; kt++) bfr[kt] = *(const short8*)(wrow + kt * 32);
      f32x4 acc[2];
      acc[0] = (f32x4){0.f, 0.f, 0.f, 0.f};
      acc[1] = (f32x4){0.f, 0.f, 0.f, 0.f};
      #pragma unroll
      for (int kt = 0; kt < 4; kt++) {
        acc[0] = __builtin_amdgcn_mfma_f32_16x16x32_bf16(afr[0][kt], bfr[kt], acc[0], 0, 0, 0);
        acc[1] = __builtin_amdgcn_mfma_f32_16x16x32_bf16(afr[1][kt], bfr[kt], acc[1], 0, 0, 0);
      }
      float bj = b1[j];
      #pragma unroll
      for (int rt = 0; rt < 2; rt++)
        #pragma unroll
        for (int r = 0; r < 4; r++) {
          int nl = rt * 16 + lg * 4 + r;
          float tv = fmaxf(acc[rt][r] + bj, 0.f);
          tS[nl][(((j >> 3) ^ (nl & 7)) * 8) + (j & 7)] = (short)f2bf(tv);
        }
    }
  }
  __syncthreads();
  // ---- GEMM2: t [32 x 512] @ W2^T -> [32 x 128], +b2, +xn residual ---------
  {
    for (int ci = 0; ci < 2; ci++) {
      int c = (w * 2 + ci) * 16 + ll;
      const unsigned short* wrow = w2b + (size_t)c * 512 + lg * 8;
      short8 bfr[16];
      #pragma unroll
      for (int kt = 0; kt < 16; kt++) bfr[kt] = *(const short8*)(wrow + kt * 32);
      float bj = b2[c];
      #pragma unroll
      for (int rt = 0; rt < 2; rt++) {
        int arow = rt * 16 + ll;
        f32x4 acc = {0.f, 0.f, 0.f, 0.f};
        #pragma unroll
        for (int kt = 0; kt < 16; kt++) {
          short8 a = *(const short8*)&tS[arow][((kt * 4 + lg) ^ (ll & 7)) * 8];
          acc = __builtin_amdgcn_mfma_f32_16x16x32_bf16(a, bfr[kt], acc, 0, 0, 0);
        }
        #pragma unroll
        for (int r = 0; r < 4; r++) {
          int node = node0 + rt * 16 + lg * 4 + r;
          if (node < n)
            out[(size_t)node * HID + c] =
                bf2f(xnb[(size_t)node * HID + c]) + acc[r] + bj;
        }
      }
    }
  }
}

extern "C" void kernel_launch(void* const* d_in, const int* in_sizes, int n_in,
                              void* d_out, int out_size, void* d_ws, size_t ws_size,
                              hipStream_t stream) {
  const float* x     = (const float*)d_in[0];
  const int*   ei    = (const int*)d_in[1];
  const float* attr  = (const float*)d_in[2];
  const float* ln1_g = (const float*)d_in[3];
  const float* ln1_b = (const float*)d_in[4];
  const float* Wq    = (const float*)d_in[5];
  const float* bq    = (const float*)d_in[6];
  const float* Wk    = (const float*)d_in[7];
  const float* bk    = (const float*)d_in[8];
  const float* Wv    = (const float*)d_in[9];
  const float* bv    = (const float*)d_in[10];
  const float* We    = (const float*)d_in[11];
  const float* Wskip = (const float*)d_in[12];
  const float* bskip = (const float*)d_in[13];
  const float* Wbeta = (const float*)d_in[14];
  const float* ln2_g = (const float*)d_in[15];
  const float* ln2_b = (const float*)d_in[16];
  const float* W1    = (const float*)d_in[17];
  const float* b1    = (const float*)d_in[18];
  const float* W2    = (const float*)d_in[19];
  const float* b2    = (const float*)d_in[20];
  float* out = (float*)d_out;
  float* ws  = (float*)d_ws;

  size_t NH  = (size_t)N_NODES * HID;  // 6.4M elements
  size_t NHf = NH / 2;                 // ushort array size in float units
  unsigned short* sb  = (unsigned short*)ws;             // [N][128] bf16 skip
  unsigned short* xnb = (unsigned short*)(ws + NHf);     // [N][128] bf16 xn
  unsigned short* qb  = (unsigned short*)(ws + 2 * NHf); // [N][128] bf16 q
  unsigned char*  kvb = (unsigned char*)(ws + 3 * NHf);  // [N][256] fp8 k|v
  float* base2 = ws + 3 * NHf + (size_t)N_NODES * 256 / 4;
  int* deg       = (int*)base2;
  int* row_start = deg + N_NODES;
  int* cursor    = row_start + N_NODES;
  int* csr_src   = cursor + N_NODES;
  // 3*N + E ints = 950000 (multiple of 4) -> csr_attr stays 16B-aligned
  float4* csr_attr = (float4*)(base2 + 950000);
  unsigned short* wqkvs = (unsigned short*)(base2 + 950000 + (size_t)E_EDGES * 4);
  unsigned short* w1b   = wqkvs + 65536;
  unsigned short* w2b   = w1b + 65536;

  hipMemsetAsync(deg, 0, N_NODES * sizeof(int), stream);

  wcvt_kernel<<<192, 256, 0, stream>>>(
      (const float4*)Wq, (const float4*)Wk, (const float4*)Wv,
      (const float4*)Wskip, (const float4*)W1, (const float4*)W2,
      wqkvs, w1b, w2b);
  qkvs_kernel<<<2 * NQB, 256, 0, stream>>>(
      x, ln1_g, ln1_b, wqkvs, bq, bk, bv, bskip, qb, kvb, sb, ei, deg, N_NODES);
  scan_kernel<<<1, 1024, 0, stream>>>(deg, row_start, cursor, N_NODES);
  scatter_kernel<<<(E_EDGES + 255) / 256, 256, 0, stream>>>(
      ei, (const float4*)attr, cursor, csr_src, csr_attr);
  gather_kernel<<<(N_NODES * 64 + 255) / 256, 256, 0, stream>>>(
      row_start, deg, csr_src, csr_attr, We, qb, kvb, x, sb, Wbeta, xnb, N_NODES);
  mlp_kernel<<<(N_NODES + 31) / 32, 256, 0, stream>>>(
      xnb, ln2_g, ln2_b, w1b, b1, w2b, b2, out, N_NODES);
}